// Round 8
// baseline (515.817 us; speedup 1.0000x reference)
//
#include <hip/hip_runtime.h>
#include <hip/hip_bf16.h>

typedef __bf16 bf16_t;
typedef __bf16 bf16x8 __attribute__((ext_vector_type(8)));
typedef __bf16 bf16x4 __attribute__((ext_vector_type(4)));
typedef float f32x4 __attribute__((ext_vector_type(4)));
typedef float f32x16 __attribute__((ext_vector_type(16)));

#define MFMA16(a, b, c) __builtin_amdgcn_mfma_f32_16x16x32_bf16((a), (b), (c), 0, 0, 0)
#define MFMA32(a, b, c) __builtin_amdgcn_mfma_f32_32x32x16_bf16((a), (b), (c), 0, 0, 0)

#define WN 393216  // elems per weight matrix (512*768)
#define VP_ELEMS 14680064ULL   // 128 q * 224 frags * 512
#define TP_ELEMS 4194304ULL    // 128 b * 64 frags * 512

// load 8 consecutive f32, round to bf16x8 (RNE)
__device__ inline bf16x8 cvt8(const float* __restrict__ p) {
    f32x4 a = *reinterpret_cast<const f32x4*>(p);
    f32x4 b = *reinterpret_cast<const f32x4*>(p + 4);
    bf16x8 r;
    r[0] = (bf16_t)a[0]; r[1] = (bf16_t)a[1]; r[2] = (bf16_t)a[2]; r[3] = (bf16_t)a[3];
    r[4] = (bf16_t)b[0]; r[5] = (bf16_t)b[1]; r[6] = (bf16_t)b[2]; r[7] = (bf16_t)b[3];
    return r;
}

// async global->LDS DMA, 16 B/lane; LDS dest = wave-uniform base + lane*16
__device__ __forceinline__ void gload_lds16(const bf16_t* g, bf16_t* l) {
    __builtin_amdgcn_global_load_lds(
        (const __attribute__((address_space(1))) void*)g,
        (__attribute__((address_space(3))) void*)l, 16, 0, 0);
}

// ---------------------------------------------------------------------------
// All 4 weight matrices f32 -> bf16, PACKED in MFMA-fragment-linear order:
//   P[seg][(ec*8 + t)*24 + k][lane][j]  (512 bf16 per frag)
//   <- W[seg][ec*128 + t*16 + (lane&15)][k*32 + (lane>>4)*8 + j]
// so proj_all's per-(t,k) W load is one contiguous 1 KiB wave stream at
// lane*16 B (was: 16-row-scattered, 16-32 cache lines per instr).
// ---------------------------------------------------------------------------
__global__ __launch_bounds__(256) void cvt_w4(
    const float* __restrict__ s0, const float* __restrict__ s1,
    const float* __restrict__ s2, const float* __restrict__ s3,
    bf16_t* __restrict__ d)
{
    int g = blockIdx.x * 256 + threadIdx.x;   // 8-elem group, < 196608
    int seg = g / 49152;                      // WN/8
    int rem = g - seg * 49152;
    int frag = rem >> 6;                      // (ec*8+t)*24 + k, 0..767
    int lane = rem & 63;
    int k  = frag % 24;
    int et = frag / 24;                       // ec*8 + t, 0..31
    int row = et * 16 + (lane & 15);          // = ec*128 + t*16 + l16
    int col = k * 32 + (lane >> 4) * 8;
    const float* s = (seg == 0) ? s0 : (seg == 1) ? s1 : (seg == 2) ? s2 : s3;
    bf16x8 r = cvt8(s + (size_t)row * 768 + col);
    *reinterpret_cast<bf16x8*>(d + (size_t)g * 8) = r;
}

// ---------------------------------------------------------------------------
// Zero the vt=6 tail fragments of the ve pack (v >= 196 lanes). Runs BEFORE
// proj_all so valid (n<4) sub-slots get overwritten with real data.
// ---------------------------------------------------------------------------
__global__ __launch_bounds__(256) void zero_tail(bf16_t* __restrict__ vp)
{
    int i = blockIdx.x * 256 + threadIdx.x;   // bf16x8 store index, < 262144
    int off = (i & 63) * 8;                   // elem within frag (512)
    int ks  = (i >> 6) & 3;
    int c   = (i >> 8) & 7;
    int q   = i >> 11;                        // < 128
    size_t addr = ((size_t)q * 224 + c * 28 + 24 + ks) * 512 + off;
    *reinterpret_cast<f32x4*>(vp + addr) = (f32x4){0.f, 0.f, 0.f, 0.f};
}

// ---------------------------------------------------------------------------
// Merged projection v2 (R7 version, unchanged): W fragment-packed reads +
// A staged once in LDS bf16 (XOR-swizzled). Bit-identical outputs.
// ---------------------------------------------------------------------------
template<int PACKED>
__global__ __launch_bounds__(256, 2) void proj_all(
    const float* __restrict__ vtok, const float* __restrict__ ttok,
    const float* __restrict__ vcls, const float* __restrict__ tcls,
    const bf16_t* __restrict__ w_all,   // packed [4][768 frags][512]
    const float* __restrict__ bvc, const float* __restrict__ btc,
    const float* __restrict__ bvt, const float* __restrict__ btt,
    float* __restrict__ out_base,       // d_out f32
    bf16_t* __restrict__ bve, bf16_t* __restrict__ bte)
{
    const int tid  = threadIdx.x;
    const int wave = tid >> 6;          // = ec (e-slice 128*wave)
    const int lane = tid & 63;
    const int l16  = lane & 15;
    const int quad = lane >> 4;
    const int e0   = wave * 128;
    const int id   = blockIdx.x;

    const float* A; const bf16_t* W; const float* bias;
    float* out; bf16_t* outb; int seg, m0;
    if (id < 784)       { seg = 0; A = vtok; W = w_all + 2 * WN; bias = bvt;
                          out = out_base + 131072;   outb = bve; m0 = id * 32; }
    else if (id < 1040) { seg = 1; A = ttok; W = w_all + 3 * WN; bias = btt;
                          out = out_base + 12976128; outb = bte; m0 = (id - 784) * 32; }
    else if (id < 1044) { seg = 2; A = vcls; W = w_all;          bias = bvc;
                          out = out_base;             outb = nullptr; m0 = (id - 1040) * 32; }
    else                { seg = 3; A = tcls; W = w_all + WN;     bias = btc;
                          out = out_base + 65536;     outb = nullptr; m0 = (id - 1044) * 32; }

    // ---- stage A tile (32 rows x 768) to LDS bf16, XOR-swizzled ----
    __shared__ bf16_t As[32 * 768];     // 48 KiB
#pragma unroll
    for (int it = 0; it < 12; ++it) {
        int idx = it * 256 + tid;       // 16B-granule id, < 3072
        int row = idx / 96;
        int cg  = idx - row * 96;
        bf16x8 v = cvt8(A + (size_t)(m0 + row) * 768 + cg * 8);
        int byte = (row * 1536 + cg * 16) ^ ((row & 7) << 4);
        *reinterpret_cast<bf16x8*>(reinterpret_cast<char*>(As) + byte) = v;
    }
    __syncthreads();

    f32x4 acc[2][8];
#pragma unroll
    for (int rt = 0; rt < 2; ++rt)
#pragma unroll
        for (int t = 0; t < 8; ++t) acc[rt][t] = (f32x4){0.f, 0.f, 0.f, 0.f};

    const bf16_t* wb = W + (size_t)(wave * 8) * 24 * 512 + lane * 8;
    const int axor = (l16 & 7) << 4;    // (l16+16)&7 == l16&7

    for (int k = 0; k < 24; ++k) {
        int b0 = ((l16)      * 1536 + (k * 4 + quad) * 16) ^ axor;
        int b1 = ((l16 + 16) * 1536 + (k * 4 + quad) * 16) ^ axor;
        bf16x8 a0 = *reinterpret_cast<const bf16x8*>(
            reinterpret_cast<const char*>(As) + b0);
        bf16x8 a1 = *reinterpret_cast<const bf16x8*>(
            reinterpret_cast<const char*>(As) + b1);
#pragma unroll
        for (int t = 0; t < 8; ++t) {
            bf16x8 wv = *reinterpret_cast<const bf16x8*>(
                wb + (size_t)(t * 24 + k) * 512);
            acc[0][t] = MFMA16(a0, wv, acc[0][t]);
            acc[1][t] = MFMA16(a1, wv, acc[1][t]);
        }
    }

#pragma unroll
    for (int t = 0; t < 8; ++t) {
        float bv = bias[e0 + t * 16 + l16];
#pragma unroll
        for (int rt = 0; rt < 2; ++rt)
#pragma unroll
            for (int r = 0; r < 4; ++r) acc[rt][t][r] += bv;
    }

    float inv[2][4];
#pragma unroll
    for (int rt = 0; rt < 2; ++rt)
#pragma unroll
        for (int r = 0; r < 4; ++r) inv[rt][r] = 1.f;

    __shared__ float sq[4][32];
    if (seg <= 1) {
#pragma unroll
        for (int rt = 0; rt < 2; ++rt)
#pragma unroll
            for (int r = 0; r < 4; ++r) {
                float s = 0.f;
#pragma unroll
                for (int t = 0; t < 8; ++t) s += acc[rt][t][r] * acc[rt][t][r];
                s += __shfl_xor(s, 1);
                s += __shfl_xor(s, 2);
                s += __shfl_xor(s, 4);
                s += __shfl_xor(s, 8);
                if (l16 == 0) sq[wave][rt * 16 + quad * 4 + r] = s;
            }
        __syncthreads();
#pragma unroll
        for (int rt = 0; rt < 2; ++rt)
#pragma unroll
            for (int r = 0; r < 4; ++r) {
                int row = rt * 16 + quad * 4 + r;
                float tot = sq[0][row] + sq[1][row] + sq[2][row] + sq[3][row];
                inv[rt][r] = 1.0f / fmaxf(sqrtf(tot), 1e-12f);
            }
    }

#pragma unroll
    for (int rt = 0; rt < 2; ++rt)
#pragma unroll
        for (int r = 0; r < 4; ++r) {
            const int   R  = m0 + rt * 16 + quad * 4 + r;
            const float is = inv[rt][r];
            const size_t lin = (size_t)R * 512 + e0 + l16;
#pragma unroll
            for (int t = 0; t < 8; ++t)
                out[lin + t * 16] = acc[rt][t][r] * is;

            if (seg <= 1) {
                if (!PACKED) {
#pragma unroll
                    for (int t = 0; t < 8; ++t)
                        outb[lin + t * 16] = (bf16_t)(acc[rt][t][r] * is);
                } else {
                    size_t fb0; int elem, stride_c;
                    if (seg == 0) {
                        int qq = R / 196, vv = R - qq * 196;
                        fb0  = (size_t)qq * 224 + (vv >> 5) * 4;
                        elem = (((l16 >> 3) * 32 + (vv & 31)) << 3) | (l16 & 7);
                        stride_c = 28;
                    } else {
                        int bb = R >> 6;
                        fb0  = (size_t)bb * 64 + ((R >> 5) & 1) * 4;
                        elem = (((l16 >> 3) * 32 + (R & 31)) << 3) | (l16 & 7);
                        stride_c = 8;
                    }
#pragma unroll
                    for (int t = 0; t < 8; ++t) {
                        int c  = wave * 2 + (t >> 2);
                        int ks = t & 3;
                        outb[(fb0 + (size_t)c * stride_c + ks) * 512 + elem] =
                            (bf16_t)(acc[rt][t][r] * is);
                    }
                }
            }
        }
}

// ---------------------------------------------------------------------------
// MaxSim v12 = v9 + co-resident-block phase stagger. v9 measured 304 us with
// LDS pipe at ~50% utilization (wall 5700 cyc/chunk vs 2900 LDS floor): both
// co-resident blocks are barrier-locked to the same cadence, so all 16 waves
// of a CU burst ds_reads/A-loads simultaneously, then all wait together.
// Fix: one-time s_sleep (~2880 cyc = half a chunk wall) for blocks with
// blockIdx bit 8 set (distinguishes the CU-assignment halves under
// round-robin dispatch) -> anti-phase bursts, one block's LDS burst fills
// the other's VMEM/barrier tail. No numeric change (sleep only).
// ---------------------------------------------------------------------------
__global__ __launch_bounds__(512, 4) void maxsim32p(
    const bf16_t* __restrict__ tp,  // [128][64][512] packed
    const bf16_t* __restrict__ vp,  // [128][224][512] packed
    float* __restrict__ sim)        // [128,128] (b major)
{
    const int tid  = threadIdx.x;
    const int wave = tid >> 6;
    const int lane = tid & 63;
    const int l32  = lane & 31;
    const int h    = lane >> 5;
    const int vh   = wave >> 2;             // 0: vt 0..3, 1: vt 4..6
    const int bhat = (wave >> 1) & 1;
    const int tt   = wave & 1;
    const int vt0  = vh * 4;

    const int n  = blockIdx.x;
    const int q  = n >> 6;
    const int bp = n & 63;
    const int b  = bp * 2 + bhat;

    // Phase-stagger the co-resident block pair (bit 8 splits the two
    // CU-assignment halves under 8-XCD round-robin dispatch).
    if ((n >> 8) & 1) asm volatile("s_sleep 45");

    __shared__ bf16_t vs[2][14336];         // 2 x 28 KiB (28 frags x 512)
    float* red = (float*)(void*)&vs[0][0];  // aliased after c=7 barrier

    f32x16 acc[4];                          // vh1 uses only 3
#pragma unroll
    for (int j = 0; j < 4; ++j)
#pragma unroll
        for (int r = 0; r < 16; ++r) acc[j][r] = 0.f;

    const bf16_t* vq = vp + (size_t)q * 114688;   // 224*512
    const bf16_t* tb = tp + (size_t)b * 32768;    // 64*512

    auto issue = [&](int buf, int c) {
#pragma unroll
        for (int g = 0; g < 4; ++g) {            // frags wave, wave+8, +16, +24
            int f = wave + g * 8;
            if (f < 28)
                gload_lds16(vq + (size_t)c * 14336 + f * 512 + lane * 8,
                            &vs[buf][f * 512]);
        }
    };

    issue(0, 0);
#pragma unroll
    for (int c = 0; c < 8; ++c) {
        __syncthreads();                          // buf c&1 DMA complete
        if (c < 7) issue((c + 1) & 1, c + 1);
        bf16x8 a[4];
        const bf16_t* ta = tb + (size_t)(c * 8 + tt * 4) * 512 + lane * 8;
#pragma unroll
        for (int ks = 0; ks < 4; ++ks)
            a[ks] = *reinterpret_cast<const bf16x8*>(ta + ks * 512);
        const bf16_t* bbase = &vs[c & 1][vt0 * 2048 + lane * 8];
#pragma unroll
        for (int ks = 0; ks < 4; ++ks) {
#pragma unroll
            for (int j = 0; j < 3; ++j) {
                bf16x8 bv = *reinterpret_cast<const bf16x8*>(
                    bbase + (j * 4 + ks) * 512);
                acc[j] = MFMA32(a[ks], bv, acc[j]);
            }
            if (vh == 0) {                        // j=3 (vt3), uniform branch
                bf16x8 bv = *reinterpret_cast<const bf16x8*>(
                    bbase + (12 + ks) * 512);
                acc[3] = MFMA32(a[ks], bv, acc[3]);
            }
        }
    }

    // ---- reductions. All waves passed the c=7 barrier (vs[0] dead). ----
#pragma unroll
    for (int reg = 0; reg < 16; ++reg) {
        float m = fmaxf(acc[0][reg], acc[1][reg]);
        if (vh == 0) {
            m = fmaxf(m, acc[2][reg]);
            m = fmaxf(m, acc[3][reg]);
        } else if (l32 < 4) {
            m = fmaxf(m, acc[2][reg]);            // vt6: cols 192..195 valid
        }
        m = fmaxf(m, __shfl_xor(m, 1));
        m = fmaxf(m, __shfl_xor(m, 2));
        m = fmaxf(m, __shfl_xor(m, 4));
        m = fmaxf(m, __shfl_xor(m, 8));
        m = fmaxf(m, __shfl_xor(m, 16));
        if (l32 == 0) {
            int row = tt * 32 + (reg & 3) + 8 * (reg >> 2) + 4 * h;
            red[(bhat * 2 + vh) * 64 + row] = m;
        }
    }
#pragma unroll
    for (int j = 0; j < 3; ++j) {
        float m = acc[j][0];
#pragma unroll
        for (int reg = 1; reg < 16; ++reg) m = fmaxf(m, acc[j][reg]);
        m = fmaxf(m, __shfl_xor(m, 32));          // combine h halves
        if (h == 0) red[256 + (bhat * 2 + tt) * 224 + (vt0 + j) * 32 + l32] = m;
    }
    if (vh == 0) {                                // j=3 (vt3)
        float m = acc[3][0];
#pragma unroll
        for (int reg = 1; reg < 16; ++reg) m = fmaxf(m, acc[3][reg]);
        m = fmaxf(m, __shfl_xor(m, 32));
        if (h == 0) red[256 + (bhat * 2 + tt) * 224 + 3 * 32 + l32] = m;
    }
    __syncthreads();

    if (wave == 0) {
#pragma unroll
        for (int bi = 0; bi < 2; ++bi) {
            float t = fmaxf(red[(bi * 2 + 0) * 64 + lane],
                            red[(bi * 2 + 1) * 64 + lane]);
            float cc = 0.f;
            for (int v = lane; v < 196; v += 64)
                cc += fmaxf(red[256 + (bi * 2 + 0) * 224 + v],
                            red[256 + (bi * 2 + 1) * 224 + v]);
#pragma unroll
            for (int mk = 1; mk <= 32; mk <<= 1) {
                t  += __shfl_xor(t, mk);
                cc += __shfl_xor(cc, mk);
            }
            if (lane == 0)
                sim[(size_t)(bp * 2 + bi) * 128 + q] =
                    0.5f * (t * (1.0f / 196.0f) + cc * (1.0f / 64.0f));
        }
    }
}

// ---------------------------------------------------------------------------
// MaxSim v5 (legacy linear-mirror path, tier-1 ws fallback) — unchanged.
// ---------------------------------------------------------------------------
__global__ __launch_bounds__(256) void maxsim32(
    const bf16_t* __restrict__ te,  // [128,64,512]
    const bf16_t* __restrict__ ve,  // [128,196,512]
    float* __restrict__ sim)        // [128,128] (b major)
{
    const int tid  = threadIdx.x;
    const int wave = tid >> 6;
    const int lane = tid & 63;
    const int l32  = lane & 31;
    const int h    = lane >> 5;
    const int bhat = wave >> 1;
    const int tt   = wave & 1;

    const int n  = blockIdx.x;
    const int q  = n >> 6;
    const int bp = n & 63;
    const int b  = bp * 2 + bhat;

    __shared__ bf16_t vs[2][224 * 64];
    __shared__ float  tmax_s[2][64];
    __shared__ float  vmax_s[2][2][224];

    f32x16 acc[7];
#pragma unroll
    for (int vt = 0; vt < 7; ++vt)
#pragma unroll
        for (int r = 0; r < 16; ++r) acc[vt][r] = 0.f;

    auto issue = [&](int buf, int c) {
        for (int g = wave; g < 28; g += 4) {
            int r   = g * 8 + (lane >> 3);
            int sr  = r < 196 ? r : 195;
            int seg = (lane & 7) ^ (lane >> 3);
            gload_lds16(ve + ((size_t)q * 196 + sr) * 512 + c * 64 + seg * 8,
                        &vs[buf][g * 512]);
        }
    };

    const size_t tbase = ((size_t)b * 64 + tt * 32 + l32) * 512;

    issue(0, 0);
#pragma unroll
    for (int c = 0; c < 8; ++c) {
        __syncthreads();
        if (c < 7) issue((c + 1) & 1, c + 1);
        bf16x8 a[4];
#pragma unroll
        for (int ks = 0; ks < 4; ++ks)
            a[ks] = *reinterpret_cast<const bf16x8*>(
                te + tbase + c * 64 + ks * 16 + h * 8);
        const int buf = c & 1;
#pragma unroll
        for (int ks = 0; ks < 4; ++ks)
#pragma unroll
            for (int vt = 0; vt < 7; ++vt) {
                int row  = vt * 32 + l32;
                int phys = (ks * 2 + h) ^ (row & 7);
                bf16x8 bv = *reinterpret_cast<const bf16x8*>(
                    &vs[buf][row * 64 + phys * 8]);
                acc[vt] = MFMA32(a[ks], bv, acc[vt]);
            }
    }

#pragma unroll
    for (int reg = 0; reg < 16; ++reg) {
        float m = acc[0][reg];
#pragma unroll
        for (int vt = 1; vt < 6; ++vt) m = fmaxf(m, acc[vt][reg]);
        if (l32 < 4) m = fmaxf(m, acc[6][reg]);
        m = fmaxf(m, __shfl_xor(m, 1));
        m = fmaxf(m, __shfl_xor(m, 2));
        m = fmaxf(m, __shfl_xor(m, 4));
        m = fmaxf(m, __shfl_xor(m, 8));
        m = fmaxf(m, __shfl_xor(m, 16));
        if (l32 == 0) {
            int row = tt * 32 + (reg & 3) + 8 * (reg >> 2) + 4 * h;
            tmax_s[bhat][row] = m;
        }
    }
#pragma unroll
    for (int vt = 0; vt < 7; ++vt) {
        float m = acc[vt][0];
#pragma unroll
        for (int reg = 1; reg < 16; ++reg) m = fmaxf(m, acc[vt][reg]);
        m = fmaxf(m, __shfl_xor(m, 32));
        if (h == 0) vmax_s[bhat][tt][vt * 32 + l32] = m;
    }
    __syncthreads();

    if (wave == 0) {
        float t0 = tmax_s[0][lane];
        float t1 = tmax_s[1][lane];
        float c0 = 0.f, c1 = 0.f;
        for (int v = lane; v < 196; v += 64) {
            c0 += fmaxf(vmax_s[0][0][v], vmax_s[0][1][v]);
            c1 += fmaxf(vmax_s[1][0][v], vmax_s[1][1][v]);
        }
#pragma unroll
        for (int mk = 1; mk <= 32; mk <<= 1) {
            t0 += __shfl_xor(t0, mk);
            t1 += __shfl_xor(t1, mk);
            c0 += __shfl_xor(c0, mk);
            c1 += __shfl_xor(c1, mk);
        }
        if (lane == 0) {
            sim[(size_t)(bp * 2 + 0) * 128 + q] = 0.5f * (t0 * (1.0f / 196.0f) + c0 * (1.0f / 64.0f));
            sim[(size_t)(bp * 2 + 1) * 128 + q] = 0.5f * (t1 * (1.0f / 196.0f) + c1 * (1.0f / 64.0f));
        }
    }
}

// ---------------------------------------------------------------------------
// Fallback projection (f32 weights, 16-row blocks) — used only if ws too small
// ---------------------------------------------------------------------------
__global__ __launch_bounds__(256) void proj_fb(
    const float* __restrict__ A, const float* __restrict__ Wf,
    const float* __restrict__ bias, float* __restrict__ out, int do_l2)
{
    const int tid  = threadIdx.x;
    const int wave = tid >> 6;
    const int lane = tid & 63;
    const int l16  = lane & 15;
    const int quad = lane >> 4;
    const int m0   = blockIdx.x * 16;
    const int e0   = wave * 128;

    f32x4 acc[8];
#pragma unroll
    for (int t = 0; t < 8; ++t) acc[t] = (f32x4){0.f, 0.f, 0.f, 0.f};
    const float* arow = A + (size_t)(m0 + l16) * 768 + quad * 8;
    for (int k0 = 0; k0 < 768; k0 += 32) {
        bf16x8 af = cvt8(arow + k0);
#pragma unroll
        for (int t = 0; t < 8; ++t) {
            bf16x8 wv = cvt8(Wf + (size_t)(e0 + t * 16 + l16) * 768 + quad * 8 + k0);
            acc[t] = MFMA16(af, wv, acc[t]);
        }
    }
#pragma unroll
    for (int t = 0; t < 8; ++t) {
        float bv = bias[e0 + t * 16 + l16];
#pragma unroll
        for (int r = 0; r < 4; ++r) acc[t][r] += bv;
    }
    float inv[4] = {1.f, 1.f, 1.f, 1.f};
    __shared__ float sq[4][16];
    if (do_l2) {
#pragma unroll
        for (int r = 0; r < 4; ++r) {
            float s = 0.f;
#pragma unroll
            for (int t = 0; t < 8; ++t) s += acc[t][r] * acc[t][r];
            s += __shfl_xor(s, 1); s += __shfl_xor(s, 2);
            s += __shfl_xor(s, 4); s += __shfl_xor(s, 8);
            if (l16 == 0) sq[wave][quad * 4 + r] = s;
        }
        __syncthreads();
#pragma unroll
        for (int r = 0; r < 4; ++r) {
            float tot = sq[0][quad * 4 + r] + sq[1][quad * 4 + r]
                      + sq[2][quad * 4 + r] + sq[3][quad * 4 + r];
            inv[r] = 1.0f / fmaxf(sqrtf(tot), 1e-12f);
        }
    }
#pragma unroll
    for (int t = 0; t < 8; ++t)
#pragma unroll
        for (int r = 0; r < 4; ++r)
            out[(size_t)(m0 + quad * 4 + r) * 512 + (e0 + t * 16 + l16)] =
                acc[t][r] * inv[r];
}

// ---------------------------------------------------------------------------
// Fallback maxsim (f32 operands from d_out, 16x16 path) — ws-too-small only
// ---------------------------------------------------------------------------
__global__ __launch_bounds__(256) void maxsim_fb(
    const float* __restrict__ te, const float* __restrict__ ve,
    float* __restrict__ sim)
{
    const int tid  = threadIdx.x;
    const int wave = tid >> 6;
    const int lane = tid & 63;
    const int l16  = lane & 15;
    const int quad = lane >> 4;
    const int q    = blockIdx.x >> 6;
    const int bp   = blockIdx.x & 63;

    __shared__ bf16_t vsl[208 * 72];
    __shared__ float  maxt_s[2][4][208];
    __shared__ float  t2v_part[2][4];

    f32x4 acc0[13], acc1[13];
#pragma unroll
    for (int vt = 0; vt < 13; ++vt) {
        acc0[vt] = (f32x4){0.f, 0.f, 0.f, 0.f};
        acc1[vt] = (f32x4){0.f, 0.f, 0.f, 0.f};
    }
    const size_t toff0 = ((size_t)(bp * 2) * 64 + wave * 16 + l16) * 512 + quad * 8;
    const size_t toff1 = toff0 + (size_t)64 * 512;

    for (int k0 = 0; k0 < 512; k0 += 64) {
        __syncthreads();
        for (int s = tid; s < 416; s += 256) {
            const int row  = s >> 1;
            const int half = s & 1;
            const int vsrc = row < 196 ? row : 195;
            bf16x8 tmp[4];
            const size_t goff = ((size_t)q * 196 + vsrc) * 512 + k0 + half * 32;
#pragma unroll
            for (int j = 0; j < 4; ++j) tmp[j] = cvt8(ve + goff + j * 8);
            bf16_t* dst = &vsl[row * 72 + half * 32];
#pragma unroll
            for (int j = 0; j < 4; ++j)
                *reinterpret_cast<bf16x8*>(dst + j * 8) = tmp[j];
        }
        __syncthreads();
#pragma unroll
        for (int ks = 0; ks < 2; ++ks) {
            bf16x8 a0 = cvt8(te + toff0 + k0 + ks * 32);
            bf16x8 a1 = cvt8(te + toff1 + k0 + ks * 32);
#pragma unroll
            for (int vt = 0; vt < 13; ++vt) {
                bf16x8 bv = *reinterpret_cast<const bf16x8*>(
                    &vsl[(vt * 16 + l16) * 72 + ks * 32 + quad * 8]);
                acc0[vt] = MFMA16(a0, bv, acc0[vt]);
                acc1[vt] = MFMA16(a1, bv, acc1[vt]);
            }
        }
    }
#pragma unroll
    for (int bi = 0; bi < 2; ++bi) {
        const f32x4* acc = bi ? acc1 : acc0;
        float sum_maxv = 0.f;
#pragma unroll
        for (int r = 0; r < 4; ++r) {
            float m = -3.0e38f;
#pragma unroll
            for (int vt = 0; vt < 13; ++vt) {
                int v = vt * 16 + l16;
                if (v < 196) m = fmaxf(m, acc[vt][r]);
            }
            m = fmaxf(m, __shfl_xor(m, 1));
            m = fmaxf(m, __shfl_xor(m, 2));
            m = fmaxf(m, __shfl_xor(m, 4));
            m = fmaxf(m, __shfl_xor(m, 8));
            sum_maxv += m;
        }
        sum_maxv += __shfl_xor(sum_maxv, 16);
        sum_maxv += __shfl_xor(sum_maxv, 32);
        if (lane == 0) t2v_part[bi][wave] = sum_maxv;
#pragma unroll
        for (int vt = 0; vt < 13; ++vt) {
            float m = fmaxf(fmaxf(acc[vt][0], acc[vt][1]),
                            fmaxf(acc[vt][2], acc[vt][3]));
            m = fmaxf(m, __shfl_xor(m, 16));
            m = fmaxf(m, __shfl_xor(m, 32));
            if (lane < 16) maxt_s[bi][wave][vt * 16 + l16] = m;
        }
    }
    __syncthreads();
    if (wave == 0) {
#pragma unroll
        for (int bi = 0; bi < 2; ++bi) {
            float s_row = t2v_part[bi][0] + t2v_part[bi][1]
                        + t2v_part[bi][2] + t2v_part[bi][3];
            float s_col = 0.f;
            for (int v = lane; v < 196; v += 64) {
                float m = fmaxf(fmaxf(maxt_s[bi][0][v], maxt_s[bi][1][v]),
                                fmaxf(maxt_s[bi][2][v], maxt_s[bi][3][v]));
                s_col += m;
            }
            s_col += __shfl_xor(s_col, 1);
            s_col += __shfl_xor(s_col, 2);
            s_col += __shfl_xor(s_col, 4);
            s_col += __shfl_xor(s_col, 8);
            s_col += __shfl_xor(s_col, 16);
            s_col += __shfl_xor(s_col, 32);
            if (lane == 0)
                sim[(size_t)(bp * 2 + bi) * 128 + q] =
                    0.5f * (s_row * (1.0f / 196.0f) + s_col * (1.0f / 64.0f));
        }
    }
}

// ---------------------------------------------------------------------------
// text_mask[b,t] = (t < len[b]); int64-vs-int32 auto-detect (lengths 1..64).
// ---------------------------------------------------------------------------
__global__ void mask_kernel(const int* __restrict__ len, float* __restrict__ mask)
{
    int i = blockIdx.x * 256 + threadIdx.x;
    int is64 = (len[1] == 0) ? 1 : 0;
    if (i < 128 * 64) {
        int b = i >> 6;
        int t = i & 63;
        int L = is64 ? len[2 * b] : len[b];
        mask[i] = (t < L) ? 1.0f : 0.0f;
    }
}

extern "C" void kernel_launch(void* const* d_in, const int* in_sizes, int n_in,
                              void* d_out, int out_size, void* d_ws, size_t ws_size,
                              hipStream_t stream)
{
    int idx[13] = {0, 1, 2, 3, 4, 5, 6, 7, 8, 9, 10, 11, 12};
    if (in_sizes && n_in >= 13) {
        bool dict = (in_sizes[2] == 19267584) && (in_sizes[4] == 393216);
        if (!dict) {
            static const int alpha_sizes[13] = {393216, 393216, 393216, 393216,
                                                512, 512, 512, 512, 128,
                                                98304, 6291456, 98304, 19267584};
            bool alpha = true;
            for (int i = 0; i < 13; ++i)
                if (in_sizes[i] != alpha_sizes[i]) { alpha = false; break; }
            if (alpha) {
                const int m[13] = {11, 9, 12, 10, 2, 6, 0, 4, 3, 7, 1, 5, 8};
                for (int i = 0; i < 13; ++i) idx[i] = m[i];
            }
        }
    }

    const float* visual_cls     = (const float*)d_in[idx[0]];
    const float* textual_cls    = (const float*)d_in[idx[1]];
    const float* visual_tokens  = (const float*)d_in[idx[2]];
    const float* textual_tokens = (const float*)d_in[idx[3]];
    const float* Wv_cls = (const float*)d_in[idx[4]];
    const float* bv_cls = (const float*)d_in[idx[5]];
    const float* Wt_cls = (const float*)d_in[idx[6]];
    const float* bt_cls = (const float*)d_in[idx[7]];
    const float* Wv_tok = (const float*)d_in[idx[8]];
    const float* bv_tok = (const float*)d_in[idx[9]];
    const float* Wt_tok = (const float*)d_in[idx[10]];
    const float* bt_tok = (const float*)d_in[idx[11]];
    const int*   text_length = (const int*)d_in[idx[12]];

    float* out    = (float*)d_out;
    float* o_vcls = out;
    float* o_tcls = out + 65536;
    float* o_ve   = out + 131072;
    float* o_te   = out + 12976128;
    float* o_mask = out + 17170432;
    float* o_sim  = out + 17178624;

    const size_t NVE = 12845056;   // linear bf16 ve mirror (tier-1)
    const size_t NTE = 4194304;
    const size_t need_new = (4 * (size_t)WN + VP_ELEMS + TP_ELEMS) * 2;   // 40.9 MB
    const size_t need_old = (4 * (size_t)WN + NVE + NTE) * 2;             // 37.2 MB

    dim3 blk(256);
    if (ws_size >= need_new) {
        bf16_t* w_all = (bf16_t*)d_ws;
        bf16_t* vp    = w_all + 4 * (size_t)WN;
        bf16_t* tp    = vp + VP_ELEMS;
        cvt_w4<<<768, blk, 0, stream>>>(Wv_cls, Wt_cls, Wv_tok, Wt_tok, w_all);
        zero_tail<<<1024, blk, 0, stream>>>(vp);
        proj_all<1><<<1048, blk, 0, stream>>>(visual_tokens, textual_tokens,
                                              visual_cls, textual_cls, w_all,
                                              bv_cls, bt_cls, bv_tok, bt_tok,
                                              out, vp, tp);
        mask_kernel<<<32, blk, 0, stream>>>(text_length, o_mask);
        maxsim32p<<<128 * 64, dim3(512), 0, stream>>>(tp, vp, o_sim);
    } else if (ws_size >= need_old) {
        bf16_t* w_all = (bf16_t*)d_ws;
        bf16_t* b_ve  = w_all + 4 * (size_t)WN;
        bf16_t* b_te  = b_ve + NVE;
        cvt_w4<<<768, blk, 0, stream>>>(Wv_cls, Wt_cls, Wv_tok, Wt_tok, w_all);
        proj_all<0><<<1048, blk, 0, stream>>>(visual_tokens, textual_tokens,
                                              visual_cls, textual_cls, w_all,
                                              bv_cls, bt_cls, bv_tok, bt_tok,
                                              out, b_ve, b_te);
        mask_kernel<<<32, blk, 0, stream>>>(text_length, o_mask);
        maxsim32<<<128 * 64, blk, 0, stream>>>(b_te, b_ve, o_sim);
    } else {
        proj_fb<<<8,    blk, 0, stream>>>(visual_cls,     Wv_cls, bv_cls, o_vcls, 0);
        proj_fb<<<8,    blk, 0, stream>>>(textual_cls,    Wt_cls, bt_cls, o_tcls, 0);
        proj_fb<<<1568, blk, 0, stream>>>(visual_tokens,  Wv_tok, bv_tok, o_ve, 1);
        proj_fb<<<512,  blk, 0, stream>>>(textual_tokens, Wt_tok, bt_tok, o_te, 1);
        mask_kernel<<<32, blk, 0, stream>>>(text_length, o_mask);
        maxsim_fb<<<128 * 64, blk, 0, stream>>>(o_te, o_ve, o_sim);
    }
}

// Round 11
// 515.214 us; speedup vs baseline: 1.0012x; 1.0012x over previous
//
#include <hip/hip_runtime.h>
#include <hip/hip_bf16.h>

typedef __bf16 bf16_t;
typedef __bf16 bf16x8 __attribute__((ext_vector_type(8)));
typedef __bf16 bf16x4 __attribute__((ext_vector_type(4)));
typedef float f32x4 __attribute__((ext_vector_type(4)));
typedef float f32x16 __attribute__((ext_vector_type(16)));

#define MFMA16(a, b, c) __builtin_amdgcn_mfma_f32_16x16x32_bf16((a), (b), (c), 0, 0, 0)
#define MFMA32(a, b, c) __builtin_amdgcn_mfma_f32_32x32x16_bf16((a), (b), (c), 0, 0, 0)

#define WN 393216  // elems per weight matrix (512*768)
#define VP_ELEMS 14680064ULL   // 128 q * 224 frags * 512
#define TP_ELEMS 4194304ULL    // 128 b * 64 frags * 512

// load 8 consecutive f32, round to bf16x8 (RNE)
__device__ inline bf16x8 cvt8(const float* __restrict__ p) {
    f32x4 a = *reinterpret_cast<const f32x4*>(p);
    f32x4 b = *reinterpret_cast<const f32x4*>(p + 4);
    bf16x8 r;
    r[0] = (bf16_t)a[0]; r[1] = (bf16_t)a[1]; r[2] = (bf16_t)a[2]; r[3] = (bf16_t)a[3];
    r[4] = (bf16_t)b[0]; r[5] = (bf16_t)b[1]; r[6] = (bf16_t)b[2]; r[7] = (bf16_t)b[3];
    return r;
}

// async global->LDS DMA, 16 B/lane; LDS dest = wave-uniform base + lane*16
__device__ __forceinline__ void gload_lds16(const bf16_t* g, bf16_t* l) {
    __builtin_amdgcn_global_load_lds(
        (const __attribute__((address_space(1))) void*)g,
        (__attribute__((address_space(3))) void*)l, 16, 0, 0);
}

// ---------------------------------------------------------------------------
// All 4 weight matrices f32 -> bf16, PACKED in MFMA-fragment-linear order:
//   P[seg][(ec*8 + t)*24 + k][lane][j]  (512 bf16 per frag)
//   <- W[seg][ec*128 + t*16 + (lane&15)][k*32 + (lane>>4)*8 + j]
// so proj_all's per-(t,k) W load is one contiguous 1 KiB wave stream at
// lane*16 B (was: 16-row-scattered, 16-32 cache lines per instr).
// ---------------------------------------------------------------------------
__global__ __launch_bounds__(256) void cvt_w4(
    const float* __restrict__ s0, const float* __restrict__ s1,
    const float* __restrict__ s2, const float* __restrict__ s3,
    bf16_t* __restrict__ d)
{
    int g = blockIdx.x * 256 + threadIdx.x;   // 8-elem group, < 196608
    int seg = g / 49152;                      // WN/8
    int rem = g - seg * 49152;
    int frag = rem >> 6;                      // (ec*8+t)*24 + k, 0..767
    int lane = rem & 63;
    int k  = frag % 24;
    int et = frag / 24;                       // ec*8 + t, 0..31
    int row = et * 16 + (lane & 15);          // = ec*128 + t*16 + l16
    int col = k * 32 + (lane >> 4) * 8;
    const float* s = (seg == 0) ? s0 : (seg == 1) ? s1 : (seg == 2) ? s2 : s3;
    bf16x8 r = cvt8(s + (size_t)row * 768 + col);
    *reinterpret_cast<bf16x8*>(d + (size_t)g * 8) = r;
}

// ---------------------------------------------------------------------------
// Zero the vt=6 tail fragments of the ve pack (v >= 196 lanes). Runs BEFORE
// proj_all so valid (n<4) sub-slots get overwritten with real data.
// ---------------------------------------------------------------------------
__global__ __launch_bounds__(256) void zero_tail(bf16_t* __restrict__ vp)
{
    int i = blockIdx.x * 256 + threadIdx.x;   // bf16x8 store index, < 262144
    int off = (i & 63) * 8;                   // elem within frag (512)
    int ks  = (i >> 6) & 3;
    int c   = (i >> 8) & 7;
    int q   = i >> 11;                        // < 128
    size_t addr = ((size_t)q * 224 + c * 28 + 24 + ks) * 512 + off;
    *reinterpret_cast<f32x4*>(vp + addr) = (f32x4){0.f, 0.f, 0.f, 0.f};
}

// ---------------------------------------------------------------------------
// Merged projection v2 (R7 structure): W fragment-packed reads + A staged
// once in LDS bf16 (XOR-swizzled). k-loop unroll 2 for deeper W-load
// pipelining (same accumulation order -> bit-identical outputs).
// ---------------------------------------------------------------------------
template<int PACKED>
__global__ __launch_bounds__(256, 2) void proj_all(
    const float* __restrict__ vtok, const float* __restrict__ ttok,
    const float* __restrict__ vcls, const float* __restrict__ tcls,
    const bf16_t* __restrict__ w_all,   // packed [4][768 frags][512]
    const float* __restrict__ bvc, const float* __restrict__ btc,
    const float* __restrict__ bvt, const float* __restrict__ btt,
    float* __restrict__ out_base,       // d_out f32
    bf16_t* __restrict__ bve, bf16_t* __restrict__ bte)
{
    const int tid  = threadIdx.x;
    const int wave = tid >> 6;          // = ec (e-slice 128*wave)
    const int lane = tid & 63;
    const int l16  = lane & 15;
    const int quad = lane >> 4;
    const int e0   = wave * 128;
    const int id   = blockIdx.x;

    const float* A; const bf16_t* W; const float* bias;
    float* out; bf16_t* outb; int seg, m0;
    if (id < 784)       { seg = 0; A = vtok; W = w_all + 2 * WN; bias = bvt;
                          out = out_base + 131072;   outb = bve; m0 = id * 32; }
    else if (id < 1040) { seg = 1; A = ttok; W = w_all + 3 * WN; bias = btt;
                          out = out_base + 12976128; outb = bte; m0 = (id - 784) * 32; }
    else if (id < 1044) { seg = 2; A = vcls; W = w_all;          bias = bvc;
                          out = out_base;             outb = nullptr; m0 = (id - 1040) * 32; }
    else                { seg = 3; A = tcls; W = w_all + WN;     bias = btc;
                          out = out_base + 65536;     outb = nullptr; m0 = (id - 1044) * 32; }

    // ---- stage A tile (32 rows x 768) to LDS bf16, XOR-swizzled ----
    __shared__ bf16_t As[32 * 768];     // 48 KiB
#pragma unroll
    for (int it = 0; it < 12; ++it) {
        int idx = it * 256 + tid;       // 16B-granule id, < 3072
        int row = idx / 96;
        int cg  = idx - row * 96;
        bf16x8 v = cvt8(A + (size_t)(m0 + row) * 768 + cg * 8);
        int byte = (row * 1536 + cg * 16) ^ ((row & 7) << 4);
        *reinterpret_cast<bf16x8*>(reinterpret_cast<char*>(As) + byte) = v;
    }
    __syncthreads();

    f32x4 acc[2][8];
#pragma unroll
    for (int rt = 0; rt < 2; ++rt)
#pragma unroll
        for (int t = 0; t < 8; ++t) acc[rt][t] = (f32x4){0.f, 0.f, 0.f, 0.f};

    const bf16_t* wb = W + (size_t)(wave * 8) * 24 * 512 + lane * 8;
    const int axor = (l16 & 7) << 4;    // (l16+16)&7 == l16&7

#pragma unroll 2
    for (int k = 0; k < 24; ++k) {
        int b0 = ((l16)      * 1536 + (k * 4 + quad) * 16) ^ axor;
        int b1 = ((l16 + 16) * 1536 + (k * 4 + quad) * 16) ^ axor;
        bf16x8 a0 = *reinterpret_cast<const bf16x8*>(
            reinterpret_cast<const char*>(As) + b0);
        bf16x8 a1 = *reinterpret_cast<const bf16x8*>(
            reinterpret_cast<const char*>(As) + b1);
#pragma unroll
        for (int t = 0; t < 8; ++t) {
            bf16x8 wv = *reinterpret_cast<const bf16x8*>(
                wb + (size_t)(t * 24 + k) * 512);
            acc[0][t] = MFMA16(a0, wv, acc[0][t]);
            acc[1][t] = MFMA16(a1, wv, acc[1][t]);
        }
    }

#pragma unroll
    for (int t = 0; t < 8; ++t) {
        float bv = bias[e0 + t * 16 + l16];
#pragma unroll
        for (int rt = 0; rt < 2; ++rt)
#pragma unroll
            for (int r = 0; r < 4; ++r) acc[rt][t][r] += bv;
    }

    float inv[2][4];
#pragma unroll
    for (int rt = 0; rt < 2; ++rt)
#pragma unroll
        for (int r = 0; r < 4; ++r) inv[rt][r] = 1.f;

    __shared__ float sq[4][32];
    if (seg <= 1) {
#pragma unroll
        for (int rt = 0; rt < 2; ++rt)
#pragma unroll
            for (int r = 0; r < 4; ++r) {
                float s = 0.f;
#pragma unroll
                for (int t = 0; t < 8; ++t) s += acc[rt][t][r] * acc[rt][t][r];
                s += __shfl_xor(s, 1);
                s += __shfl_xor(s, 2);
                s += __shfl_xor(s, 4);
                s += __shfl_xor(s, 8);
                if (l16 == 0) sq[wave][rt * 16 + quad * 4 + r] = s;
            }
        __syncthreads();
#pragma unroll
        for (int rt = 0; rt < 2; ++rt)
#pragma unroll
            for (int r = 0; r < 4; ++r) {
                int row = rt * 16 + quad * 4 + r;
                float tot = sq[0][row] + sq[1][row] + sq[2][row] + sq[3][row];
                inv[rt][r] = 1.0f / fmaxf(sqrtf(tot), 1e-12f);
            }
    }

#pragma unroll
    for (int rt = 0; rt < 2; ++rt)
#pragma unroll
        for (int r = 0; r < 4; ++r) {
            const int   R  = m0 + rt * 16 + quad * 4 + r;
            const float is = inv[rt][r];
            const size_t lin = (size_t)R * 512 + e0 + l16;
#pragma unroll
            for (int t = 0; t < 8; ++t)
                out[lin + t * 16] = acc[rt][t][r] * is;

            if (seg <= 1) {
                if (!PACKED) {
#pragma unroll
                    for (int t = 0; t < 8; ++t)
                        outb[lin + t * 16] = (bf16_t)(acc[rt][t][r] * is);
                } else {
                    size_t fb0; int elem, stride_c;
                    if (seg == 0) {
                        int qq = R / 196, vv = R - qq * 196;
                        fb0  = (size_t)qq * 224 + (vv >> 5) * 4;
                        elem = (((l16 >> 3) * 32 + (vv & 31)) << 3) | (l16 & 7);
                        stride_c = 28;
                    } else {
                        int bb = R >> 6;
                        fb0  = (size_t)bb * 64 + ((R >> 5) & 1) * 4;
                        elem = (((l16 >> 3) * 32 + (R & 31)) << 3) | (l16 & 7);
                        stride_c = 8;
                    }
#pragma unroll
                    for (int t = 0; t < 8; ++t) {
                        int c  = wave * 2 + (t >> 2);
                        int ks = t & 3;
                        outb[(fb0 + (size_t)c * stride_c + ks) * 512 + elem] =
                            (bf16_t)(acc[rt][t][r] * is);
                    }
                }
            }
        }
}

// ---------------------------------------------------------------------------
// MaxSim v9 (best measured: 303-304 us, Occ 41%, Mfma 35.2%). R8's s_sleep
// stagger removed (measured: cost 4%). Block = (q, b-pair), 8 waves =
// (vh = w>>2, bhat = (w>>1)&1, tt = w&1); acc = 4 x f32x16 = 64 acc-regs
// -> 4 waves/SIMD via __launch_bounds__(512, 4).
// C/D map: col v = (vh*4+j)*32 + (lane&31),
// row t-in-tile = (reg&3) + 8*(reg>>2) + 4*(lane>>5), global t = tt*32+row.
// ---------------------------------------------------------------------------
__global__ __launch_bounds__(512, 4) void maxsim32p(
    const bf16_t* __restrict__ tp,  // [128][64][512] packed
    const bf16_t* __restrict__ vp,  // [128][224][512] packed
    float* __restrict__ sim)        // [128,128] (b major)
{
    const int tid  = threadIdx.x;
    const int wave = tid >> 6;
    const int lane = tid & 63;
    const int l32  = lane & 31;
    const int h    = lane >> 5;
    const int vh   = wave >> 2;             // 0: vt 0..3, 1: vt 4..6
    const int bhat = (wave >> 1) & 1;
    const int tt   = wave & 1;
    const int vt0  = vh * 4;

    const int n  = blockIdx.x;
    const int q  = n >> 6;
    const int bp = n & 63;
    const int b  = bp * 2 + bhat;

    __shared__ bf16_t vs[2][14336];         // 2 x 28 KiB (28 frags x 512)
    float* red = (float*)(void*)&vs[0][0];  // aliased after c=7 barrier

    f32x16 acc[4];                          // vh1 uses only 3
#pragma unroll
    for (int j = 0; j < 4; ++j)
#pragma unroll
        for (int r = 0; r < 16; ++r) acc[j][r] = 0.f;

    const bf16_t* vq = vp + (size_t)q * 114688;   // 224*512
    const bf16_t* tb = tp + (size_t)b * 32768;    // 64*512

    auto issue = [&](int buf, int c) {
#pragma unroll
        for (int g = 0; g < 4; ++g) {            // frags wave, wave+8, +16, +24
            int f = wave + g * 8;
            if (f < 28)
                gload_lds16(vq + (size_t)c * 14336 + f * 512 + lane * 8,
                            &vs[buf][f * 512]);
        }
    };

    issue(0, 0);
#pragma unroll
    for (int c = 0; c < 8; ++c) {
        __syncthreads();                          // buf c&1 DMA complete
        if (c < 7) issue((c + 1) & 1, c + 1);
        bf16x8 a[4];
        const bf16_t* ta = tb + (size_t)(c * 8 + tt * 4) * 512 + lane * 8;
#pragma unroll
        for (int ks = 0; ks < 4; ++ks)
            a[ks] = *reinterpret_cast<const bf16x8*>(ta + ks * 512);
        const bf16_t* bbase = &vs[c & 1][vt0 * 2048 + lane * 8];
#pragma unroll
        for (int ks = 0; ks < 4; ++ks) {
#pragma unroll
            for (int j = 0; j < 3; ++j) {
                bf16x8 bv = *reinterpret_cast<const bf16x8*>(
                    bbase + (j * 4 + ks) * 512);
                acc[j] = MFMA32(a[ks], bv, acc[j]);
            }
            if (vh == 0) {                        // j=3 (vt3), uniform branch
                bf16x8 bv = *reinterpret_cast<const bf16x8*>(
                    bbase + (12 + ks) * 512);
                acc[3] = MFMA32(a[ks], bv, acc[3]);
            }
        }
    }

    // ---- reductions. All waves passed the c=7 barrier (vs[0] dead). ----
#pragma unroll
    for (int reg = 0; reg < 16; ++reg) {
        float m = fmaxf(acc[0][reg], acc[1][reg]);
        if (vh == 0) {
            m = fmaxf(m, acc[2][reg]);
            m = fmaxf(m, acc[3][reg]);
        } else if (l32 < 4) {
            m = fmaxf(m, acc[2][reg]);            // vt6: cols 192..195 valid
        }
        m = fmaxf(m, __shfl_xor(m, 1));
        m = fmaxf(m, __shfl_xor(m, 2));
        m = fmaxf(m, __shfl_xor(m, 4));
        m = fmaxf(m, __shfl_xor(m, 8));
        m = fmaxf(m, __shfl_xor(m, 16));
        if (l32 == 0) {
            int row = tt * 32 + (reg & 3) + 8 * (reg >> 2) + 4 * h;
            red[(bhat * 2 + vh) * 64 + row] = m;
        }
    }
#pragma unroll
    for (int j = 0; j < 3; ++j) {
        float m = acc[j][0];
#pragma unroll
        for (int reg = 1; reg < 16; ++reg) m = fmaxf(m, acc[j][reg]);
        m = fmaxf(m, __shfl_xor(m, 32));          // combine h halves
        if (h == 0) red[256 + (bhat * 2 + tt) * 224 + (vt0 + j) * 32 + l32] = m;
    }
    if (vh == 0) {                                // j=3 (vt3)
        float m = acc[3][0];
#pragma unroll
        for (int reg = 1; reg < 16; ++reg) m = fmaxf(m, acc[3][reg]);
        m = fmaxf(m, __shfl_xor(m, 32));
        if (h == 0) red[256 + (bhat * 2 + tt) * 224 + 3 * 32 + l32] = m;
    }
    __syncthreads();

    if (wave == 0) {
#pragma unroll
        for (int bi = 0; bi < 2; ++bi) {
            float t = fmaxf(red[(bi * 2 + 0) * 64 + lane],
                            red[(bi * 2 + 1) * 64 + lane]);
            float cc = 0.f;
            for (int v = lane; v < 196; v += 64)
                cc += fmaxf(red[256 + (bi * 2 + 0) * 224 + v],
                            red[256 + (bi * 2 + 1) * 224 + v]);
#pragma unroll
            for (int mk = 1; mk <= 32; mk <<= 1) {
                t  += __shfl_xor(t, mk);
                cc += __shfl_xor(cc, mk);
            }
            if (lane == 0)
                sim[(size_t)(bp * 2 + bi) * 128 + q] =
                    0.5f * (t * (1.0f / 196.0f) + cc * (1.0f / 64.0f));
        }
    }
}

// ---------------------------------------------------------------------------
// MaxSim v5 (legacy linear-mirror path, tier-1 ws fallback) — unchanged.
// ---------------------------------------------------------------------------
__global__ __launch_bounds__(256) void maxsim32(
    const bf16_t* __restrict__ te,  // [128,64,512]
    const bf16_t* __restrict__ ve,  // [128,196,512]
    float* __restrict__ sim)        // [128,128] (b major)
{
    const int tid  = threadIdx.x;
    const int wave = tid >> 6;
    const int lane = tid & 63;
    const int l32  = lane & 31;
    const int h    = lane >> 5;
    const int bhat = wave >> 1;
    const int tt   = wave & 1;

    const int n  = blockIdx.x;
    const int q  = n >> 6;
    const int bp = n & 63;
    const int b  = bp * 2 + bhat;

    __shared__ bf16_t vs[2][224 * 64];
    __shared__ float  tmax_s[2][64];
    __shared__ float  vmax_s[2][2][224];

    f32x16 acc[7];
#pragma unroll
    for (int vt = 0; vt < 7; ++vt)
#pragma unroll
        for (int r = 0; r < 16; ++r) acc[vt][r] = 0.f;

    auto issue = [&](int buf, int c) {
        for (int g = wave; g < 28; g += 4) {
            int r   = g * 8 + (lane >> 3);
            int sr  = r < 196 ? r : 195;
            int seg = (lane & 7) ^ (lane >> 3);
            gload_lds16(ve + ((size_t)q * 196 + sr) * 512 + c * 64 + seg * 8,
                        &vs[buf][g * 512]);
        }
    };

    const size_t tbase = ((size_t)b * 64 + tt * 32 + l32) * 512;

    issue(0, 0);
#pragma unroll
    for (int c = 0; c < 8; ++c) {
        __syncthreads();
        if (c < 7) issue((c + 1) & 1, c + 1);
        bf16x8 a[4];
#pragma unroll
        for (int ks = 0; ks < 4; ++ks)
            a[ks] = *reinterpret_cast<const bf16x8*>(
                te + tbase + c * 64 + ks * 16 + h * 8);
        const int buf = c & 1;
#pragma unroll
        for (int ks = 0; ks < 4; ++ks)
#pragma unroll
            for (int vt = 0; vt < 7; ++vt) {
                int row  = vt * 32 + l32;
                int phys = (ks * 2 + h) ^ (row & 7);
                bf16x8 bv = *reinterpret_cast<const bf16x8*>(
                    &vs[buf][row * 64 + phys * 8]);
                acc[vt] = MFMA32(a[ks], bv, acc[vt]);
            }
    }

#pragma unroll
    for (int reg = 0; reg < 16; ++reg) {
        float m = acc[0][reg];
#pragma unroll
        for (int vt = 1; vt < 6; ++vt) m = fmaxf(m, acc[vt][reg]);
        if (l32 < 4) m = fmaxf(m, acc[6][reg]);
        m = fmaxf(m, __shfl_xor(m, 1));
        m = fmaxf(m, __shfl_xor(m, 2));
        m = fmaxf(m, __shfl_xor(m, 4));
        m = fmaxf(m, __shfl_xor(m, 8));
        m = fmaxf(m, __shfl_xor(m, 16));
        if (l32 == 0) {
            int row = tt * 32 + (reg & 3) + 8 * (reg >> 2) + 4 * h;
            tmax_s[bhat][row] = m;
        }
    }
#pragma unroll
    for (int vt = 0; vt < 7; ++vt) {
        float m = acc[vt][0];
#pragma unroll
        for (int reg = 1; reg < 16; ++reg) m = fmaxf(m, acc[vt][reg]);
        m = fmaxf(m, __shfl_xor(m, 32));
        if (h == 0) vmax_s[bhat][tt][vt * 32 + l32] = m;
    }
    __syncthreads();

    if (wave == 0) {
        float t0 = tmax_s[0][lane];
        float t1 = tmax_s[1][lane];
        float c0 = 0.f, c1 = 0.f;
        for (int v = lane; v < 196; v += 64) {
            c0 += fmaxf(vmax_s[0][0][v], vmax_s[0][1][v]);
            c1 += fmaxf(vmax_s[1][0][v], vmax_s[1][1][v]);
        }
#pragma unroll
        for (int mk = 1; mk <= 32; mk <<= 1) {
            t0 += __shfl_xor(t0, mk);
            t1 += __shfl_xor(t1, mk);
            c0 += __shfl_xor(c0, mk);
            c1 += __shfl_xor(c1, mk);
        }
        if (lane == 0) {
            sim[(size_t)(bp * 2 + 0) * 128 + q] = 0.5f * (t0 * (1.0f / 196.0f) + c0 * (1.0f / 64.0f));
            sim[(size_t)(bp * 2 + 1) * 128 + q] = 0.5f * (t1 * (1.0f / 196.0f) + c1 * (1.0f / 64.0f));
        }
    }
}

// ---------------------------------------------------------------------------
// Fallback projection (f32 weights, 16-row blocks) — used only if ws too small
// ---------------------------------------------------------------------------
__global__ __launch_bounds__(256) void proj_fb(
    const float* __restrict__ A, const float* __restrict__ Wf,
    const float* __restrict__ bias, float* __restrict__ out, int do_l2)
{
    const int tid  = threadIdx.x;
    const int wave = tid >> 6;
    const int lane = tid & 63;
    const int l16  = lane & 15;
    const int quad = lane >> 4;
    const int m0   = blockIdx.x * 16;
    const int e0   = wave * 128;

    f32x4 acc[8];
#pragma unroll
    for (int t = 0; t < 8; ++t) acc[t] = (f32x4){0.f, 0.f, 0.f, 0.f};
    const float* arow = A + (size_t)(m0 + l16) * 768 + quad * 8;
    for (int k0 = 0; k0 < 768; k0 += 32) {
        bf16x8 af = cvt8(arow + k0);
#pragma unroll
        for (int t = 0; t < 8; ++t) {
            bf16x8 wv = cvt8(Wf + (size_t)(e0 + t * 16 + l16) * 768 + quad * 8 + k0);
            acc[t] = MFMA16(af, wv, acc[t]);
        }
    }
#pragma unroll
    for (int t = 0; t < 8; ++t) {
        float bv = bias[e0 + t * 16 + l16];
#pragma unroll
        for (int r = 0; r < 4; ++r) acc[t][r] += bv;
    }
    float inv[4] = {1.f, 1.f, 1.f, 1.f};
    __shared__ float sq[4][16];
    if (do_l2) {
#pragma unroll
        for (int r = 0; r < 4; ++r) {
            float s = 0.f;
#pragma unroll
            for (int t = 0; t < 8; ++t) s += acc[t][r] * acc[t][r];
            s += __shfl_xor(s, 1); s += __shfl_xor(s, 2);
            s += __shfl_xor(s, 4); s += __shfl_xor(s, 8);
            if (l16 == 0) sq[wave][quad * 4 + r] = s;
        }
        __syncthreads();
#pragma unroll
        for (int r = 0; r < 4; ++r) {
            float tot = sq[0][quad * 4 + r] + sq[1][quad * 4 + r]
                      + sq[2][quad * 4 + r] + sq[3][quad * 4 + r];
            inv[r] = 1.0f / fmaxf(sqrtf(tot), 1e-12f);
        }
    }
#pragma unroll
    for (int t = 0; t < 8; ++t)
#pragma unroll
        for (int r = 0; r < 4; ++r)
            out[(size_t)(m0 + quad * 4 + r) * 512 + (e0 + t * 16 + l16)] =
                acc[t][r] * inv[r];
}

// ---------------------------------------------------------------------------
// Fallback maxsim (f32 operands from d_out, 16x16 path) — ws-too-small only
// ---------------------------------------------------------------------------
__global__ __launch_bounds__(256) void maxsim_fb(
    const float* __restrict__ te, const float* __restrict__ ve,
    float* __restrict__ sim)
{
    const int tid  = threadIdx.x;
    const int wave = tid >> 6;
    const int lane = tid & 63;
    const int l16  = lane & 15;
    const int quad = lane >> 4;
    const int q    = blockIdx.x >> 6;
    const int bp   = blockIdx.x & 63;

    __shared__ bf16_t vsl[208 * 72];
    __shared__ float  maxt_s[2][4][208];
    __shared__ float  t2v_part[2][4];

    f32x4 acc0[13], acc1[13];
#pragma unroll
    for (int vt = 0; vt < 13; ++vt) {
        acc0[vt] = (f32x4){0.f, 0.f, 0.f, 0.f};
        acc1[vt] = (f32x4){0.f, 0.f, 0.f, 0.f};
    }
    const size_t toff0 = ((size_t)(bp * 2) * 64 + wave * 16 + l16) * 512 + quad * 8;
    const size_t toff1 = toff0 + (size_t)64 * 512;

    for (int k0 = 0; k0 < 512; k0 += 64) {
        __syncthreads();
        for (int s = tid; s < 416; s += 256) {
            const int row  = s >> 1;
            const int half = s & 1;
            const int vsrc = row < 196 ? row : 195;
            bf16x8 tmp[4];
            const size_t goff = ((size_t)q * 196 + vsrc) * 512 + k0 + half * 32;
#pragma unroll
            for (int j = 0; j < 4; ++j) tmp[j] = cvt8(ve + goff + j * 8);
            bf16_t* dst = &vsl[row * 72 + half * 32];
#pragma unroll
            for (int j = 0; j < 4; ++j)
                *reinterpret_cast<bf16x8*>(dst + j * 8) = tmp[j];
        }
        __syncthreads();
#pragma unroll
        for (int ks = 0; ks < 2; ++ks) {
            bf16x8 a0 = cvt8(te + toff0 + k0 + ks * 32);
            bf16x8 a1 = cvt8(te + toff1 + k0 + ks * 32);
#pragma unroll
            for (int vt = 0; vt < 13; ++vt) {
                bf16x8 bv = *reinterpret_cast<const bf16x8*>(
                    &vsl[(vt * 16 + l16) * 72 + ks * 32 + quad * 8]);
                acc0[vt] = MFMA16(a0, bv, acc0[vt]);
                acc1[vt] = MFMA16(a1, bv, acc1[vt]);
            }
        }
    }
#pragma unroll
    for (int bi = 0; bi < 2; ++bi) {
        const f32x4* acc = bi ? acc1 : acc0;
        float sum_maxv = 0.f;
#pragma unroll
        for (int r = 0; r < 4; ++r) {
            float m = -3.0e38f;
#pragma unroll
            for (int vt = 0; vt < 13; ++vt) {
                int v = vt * 16 + l16;
                if (v < 196) m = fmaxf(m, acc[vt][r]);
            }
            m = fmaxf(m, __shfl_xor(m, 1));
            m = fmaxf(m, __shfl_xor(m, 2));
            m = fmaxf(m, __shfl_xor(m, 4));
            m = fmaxf(m, __shfl_xor(m, 8));
            sum_maxv += m;
        }
        sum_maxv += __shfl_xor(sum_maxv, 16);
        sum_maxv += __shfl_xor(sum_maxv, 32);
        if (lane == 0) t2v_part[bi][wave] = sum_maxv;
#pragma unroll
        for (int vt = 0; vt < 13; ++vt) {
            float m = fmaxf(fmaxf(acc[vt][0], acc[vt][1]),
                            fmaxf(acc[vt][2], acc[vt][3]));
            m = fmaxf(m, __shfl_xor(m, 16));
            m = fmaxf(m, __shfl_xor(m, 32));
            if (lane < 16) maxt_s[bi][wave][vt * 16 + l16] = m;
        }
    }
    __syncthreads();
    if (wave == 0) {
#pragma unroll
        for (int bi = 0; bi < 2; ++bi) {
            float s_row = t2v_part[bi][0] + t2v_part[bi][1]
                        + t2v_part[bi][2] + t2v_part[bi][3];
            float s_col = 0.f;
            for (int v = lane; v < 196; v += 64) {
                float m = fmaxf(fmaxf(maxt_s[bi][0][v], maxt_s[bi][1][v]),
                                fmaxf(maxt_s[bi][2][v], maxt_s[bi][3][v]));
                s_col += m;
            }
            s_col += __shfl_xor(s_col, 1);
            s_col += __shfl_xor(s_col, 2);
            s_col += __shfl_xor(s_col, 4);
            s_col += __shfl_xor(s_col, 8);
            s_col += __shfl_xor(s_col, 16);
            s_col += __shfl_xor(s_col, 32);
            if (lane == 0)
                sim[(size_t)(bp * 2 + bi) * 128 + q] =
                    0.5f * (s_row * (1.0f / 196.0f) + s_col * (1.0f / 64.0f));
        }
    }
}

// ---------------------------------------------------------------------------
// text_mask[b,t] = (t < len[b]); int64-vs-int32 auto-detect (lengths 1..64).
// ---------------------------------------------------------------------------
__global__ void mask_kernel(const int* __restrict__ len, float* __restrict__ mask)
{
    int i = blockIdx.x * 256 + threadIdx.x;
    int is64 = (len[1] == 0) ? 1 : 0;
    if (i < 128 * 64) {
        int b = i >> 6;
        int t = i & 63;
        int L = is64 ? len[2 * b] : len[b];
        mask[i] = (t < L) ? 1.0f : 0.0f;
    }
}

extern "C" void kernel_launch(void* const* d_in, const int* in_sizes, int n_in,
                              void* d_out, int out_size, void* d_ws, size_t ws_size,
                              hipStream_t stream)
{
    int idx[13] = {0, 1, 2, 3, 4, 5, 6, 7, 8, 9, 10, 11, 12};
    if (in_sizes && n_in >= 13) {
        bool dict = (in_sizes[2] == 19267584) && (in_sizes[4] == 393216);
        if (!dict) {
            static const int alpha_sizes[13] = {393216, 393216, 393216, 393216,
                                                512, 512, 512, 512, 128,
                                                98304, 6291456, 98304, 19267584};
            bool alpha = true;
            for (int i = 0; i < 13; ++i)
                if (in_sizes[i] != alpha_sizes[i]) { alpha = false; break; }
            if (alpha) {
                const int m[13] = {11, 9, 12, 10, 2, 6, 0, 4, 3, 7, 1, 5, 8};
                for (int i = 0; i < 13; ++i) idx[i] = m[i];
            }
        }
    }

    const float* visual_cls     = (const float*)d_in[idx[0]];
    const float* textual_cls    = (const float*)d_in[idx[1]];
    const float* visual_tokens  = (const float*)d_in[idx[2]];
    const float* textual_tokens = (const float*)d_in[idx[3]];
    const float* Wv_cls = (const float*)d_in[idx[4]];
    const float* bv_cls = (const float*)d_in[idx[5]];
    const float* Wt_cls = (const float*)d_in[idx[6]];
    const float* bt_cls = (const float*)d_in[idx[7]];
    const float* Wv_tok = (const float*)d_in[idx[8]];
    const float* bv_tok = (const float*)d_in[idx[9]];
    const float* Wt_tok = (const float*)d_in[idx[10]];
    const float* bt_tok = (const float*)d_in[idx[11]];
    const int*   text_length = (const int*)d_in[idx[12]];

    float* out    = (float*)d_out;
    float* o_vcls = out;
    float* o_tcls = out + 65536;
    float* o_ve   = out + 131072;
    float* o_te   = out + 12976128;
    float* o_mask = out + 17170432;
    float* o_sim  = out + 17178624;

    const size_t NVE = 12845056;   // linear bf16 ve mirror (tier-1)
    const size_t NTE = 4194304;
    const size_t need_new = (4 * (size_t)WN + VP_ELEMS + TP_ELEMS) * 2;   // 40.9 MB
    const size_t need_old = (4 * (size_t)WN + NVE + NTE) * 2;             // 37.2 MB

    dim3 blk(256);
    if (ws_size >= need_new) {
        bf16_t* w_all = (bf16_t*)d_ws;
        bf16_t* vp    = w_all + 4 * (size_t)WN;
        bf16_t* tp    = vp + VP_ELEMS;
        cvt_w4<<<768, blk, 0, stream>>>(Wv_cls, Wt_cls, Wv_tok, Wt_tok, w_all);
        zero_tail<<<1024, blk, 0, stream>>>(vp);
        proj_all<1><<<1048, blk, 0, stream>>>(visual_tokens, textual_tokens,
                                              visual_cls, textual_cls, w_all,
                                              bv_cls, bt_cls, bv_tok, bt_tok,
                                              out, vp, tp);
        mask_kernel<<<32, blk, 0, stream>>>(text_length, o_mask);
        maxsim32p<<<128 * 64, dim3(512), 0, stream>>>(tp, vp, o_sim);
    } else if (ws_size >= need_old) {
        bf16_t* w_all = (bf16_t*)d_ws;
        bf16_t* b_ve  = w_all + 4 * (size_t)WN;
        bf16_t* b_te  = b_ve + NVE;
        cvt_w4<<<768, blk, 0, stream>>>(Wv_cls, Wt_cls, Wv_tok, Wt_tok, w_all);
        proj_all<0><<<1048, blk, 0, stream>>>(visual_tokens, textual_tokens,
                                              visual_cls, textual_cls, w_all,
                                              bv_cls, bt_cls, bv_tok, bt_tok,
                                              out, b_ve, b_te);
        mask_kernel<<<32, blk, 0, stream>>>(text_length, o_mask);
        maxsim32<<<128 * 64, blk, 0, stream>>>(b_te, b_ve, o_sim);
    } else {
        proj_fb<<<8,    blk, 0, stream>>>(visual_cls,     Wv_cls, bv_cls, o_vcls, 0);
        proj_fb<<<8,    blk, 0, stream>>>(textual_cls,    Wt_cls, bt_cls, o_tcls, 0);
        proj_fb<<<1568, blk, 0, stream>>>(visual_tokens,  Wv_tok, bv_tok, o_ve, 1);
        proj_fb<<<512,  blk, 0, stream>>>(textual_tokens, Wt_tok, bt_tok, o_te, 1);
        mask_kernel<<<32, blk, 0, stream>>>(text_length, o_mask);
        maxsim_fb<<<128 * 64, blk, 0, stream>>>(o_te, o_ve, o_sim);
    }
}

// Round 12
// 510.766 us; speedup vs baseline: 1.0099x; 1.0087x over previous
//
#include <hip/hip_runtime.h>
#include <hip/hip_bf16.h>

typedef __bf16 bf16_t;
typedef __bf16 bf16x8 __attribute__((ext_vector_type(8)));
typedef __bf16 bf16x4 __attribute__((ext_vector_type(4)));
typedef float f32x4 __attribute__((ext_vector_type(4)));
typedef float f32x16 __attribute__((ext_vector_type(16)));

#define MFMA16(a, b, c) __builtin_amdgcn_mfma_f32_16x16x32_bf16((a), (b), (c), 0, 0, 0)
#define MFMA32(a, b, c) __builtin_amdgcn_mfma_f32_32x32x16_bf16((a), (b), (c), 0, 0, 0)

#define WN 393216  // elems per weight matrix (512*768)
#define VP_ELEMS 14680064ULL   // 128 q * 224 frags * 512
#define TP_ELEMS 4194304ULL    // 128 b * 64 frags * 512

// load 8 consecutive f32, round to bf16x8 (RNE)
__device__ inline bf16x8 cvt8(const float* __restrict__ p) {
    f32x4 a = *reinterpret_cast<const f32x4*>(p);
    f32x4 b = *reinterpret_cast<const f32x4*>(p + 4);
    bf16x8 r;
    r[0] = (bf16_t)a[0]; r[1] = (bf16_t)a[1]; r[2] = (bf16_t)a[2]; r[3] = (bf16_t)a[3];
    r[4] = (bf16_t)b[0]; r[5] = (bf16_t)b[1]; r[6] = (bf16_t)b[2]; r[7] = (bf16_t)b[3];
    return r;
}

// async global->LDS DMA, 16 B/lane; LDS dest = wave-uniform base + lane*16
__device__ __forceinline__ void gload_lds16(const bf16_t* g, bf16_t* l) {
    __builtin_amdgcn_global_load_lds(
        (const __attribute__((address_space(1))) void*)g,
        (__attribute__((address_space(3))) void*)l, 16, 0, 0);
}

// ---------------------------------------------------------------------------
// All 4 weight matrices f32 -> bf16, PACKED in MFMA-fragment-linear order:
//   P[seg][(ec*8 + t)*24 + k][lane][j]  (512 bf16 per frag)
//   <- W[seg][ec*128 + t*16 + (lane&15)][k*32 + (lane>>4)*8 + j]
// ---------------------------------------------------------------------------
__global__ __launch_bounds__(256) void cvt_w4(
    const float* __restrict__ s0, const float* __restrict__ s1,
    const float* __restrict__ s2, const float* __restrict__ s3,
    bf16_t* __restrict__ d)
{
    int g = blockIdx.x * 256 + threadIdx.x;   // 8-elem group, < 196608
    int seg = g / 49152;                      // WN/8
    int rem = g - seg * 49152;
    int frag = rem >> 6;                      // (ec*8+t)*24 + k, 0..767
    int lane = rem & 63;
    int k  = frag % 24;
    int et = frag / 24;                       // ec*8 + t, 0..31
    int row = et * 16 + (lane & 15);          // = ec*128 + t*16 + l16
    int col = k * 32 + (lane >> 4) * 8;
    const float* s = (seg == 0) ? s0 : (seg == 1) ? s1 : (seg == 2) ? s2 : s3;
    bf16x8 r = cvt8(s + (size_t)row * 768 + col);
    *reinterpret_cast<bf16x8*>(d + (size_t)g * 8) = r;
}

// ---------------------------------------------------------------------------
// Zero the vt=6 tail fragments of the ve pack (v >= 196 lanes). Runs BEFORE
// proj_all so valid (n<4) sub-slots get overwritten with real data.
// ---------------------------------------------------------------------------
__global__ __launch_bounds__(256) void zero_tail(bf16_t* __restrict__ vp)
{
    int i = blockIdx.x * 256 + threadIdx.x;   // bf16x8 store index, < 262144
    int off = (i & 63) * 8;                   // elem within frag (512)
    int ks  = (i >> 6) & 3;
    int c   = (i >> 8) & 7;
    int q   = i >> 11;                        // < 128
    size_t addr = ((size_t)q * 224 + c * 28 + 24 + ks) * 512 + off;
    *reinterpret_cast<f32x4*>(vp + addr) = (f32x4){0.f, 0.f, 0.f, 0.f};
}

// ---------------------------------------------------------------------------
// Merged projection v2 (R7 structure): W fragment-packed reads + A staged
// once in LDS bf16 (XOR-swizzled). k-loop unroll 2. Bit-identical outputs.
// ---------------------------------------------------------------------------
template<int PACKED>
__global__ __launch_bounds__(256, 2) void proj_all(
    const float* __restrict__ vtok, const float* __restrict__ ttok,
    const float* __restrict__ vcls, const float* __restrict__ tcls,
    const bf16_t* __restrict__ w_all,   // packed [4][768 frags][512]
    const float* __restrict__ bvc, const float* __restrict__ btc,
    const float* __restrict__ bvt, const float* __restrict__ btt,
    float* __restrict__ out_base,       // d_out f32
    bf16_t* __restrict__ bve, bf16_t* __restrict__ bte)
{
    const int tid  = threadIdx.x;
    const int wave = tid >> 6;          // = ec (e-slice 128*wave)
    const int lane = tid & 63;
    const int l16  = lane & 15;
    const int quad = lane >> 4;
    const int e0   = wave * 128;
    const int id   = blockIdx.x;

    const float* A; const bf16_t* W; const float* bias;
    float* out; bf16_t* outb; int seg, m0;
    if (id < 784)       { seg = 0; A = vtok; W = w_all + 2 * WN; bias = bvt;
                          out = out_base + 131072;   outb = bve; m0 = id * 32; }
    else if (id < 1040) { seg = 1; A = ttok; W = w_all + 3 * WN; bias = btt;
                          out = out_base + 12976128; outb = bte; m0 = (id - 784) * 32; }
    else if (id < 1044) { seg = 2; A = vcls; W = w_all;          bias = bvc;
                          out = out_base;             outb = nullptr; m0 = (id - 1040) * 32; }
    else                { seg = 3; A = tcls; W = w_all + WN;     bias = btc;
                          out = out_base + 65536;     outb = nullptr; m0 = (id - 1044) * 32; }

    // ---- stage A tile (32 rows x 768) to LDS bf16, XOR-swizzled ----
    __shared__ bf16_t As[32 * 768];     // 48 KiB
#pragma unroll
    for (int it = 0; it < 12; ++it) {
        int idx = it * 256 + tid;       // 16B-granule id, < 3072
        int row = idx / 96;
        int cg  = idx - row * 96;
        bf16x8 v = cvt8(A + (size_t)(m0 + row) * 768 + cg * 8);
        int byte = (row * 1536 + cg * 16) ^ ((row & 7) << 4);
        *reinterpret_cast<bf16x8*>(reinterpret_cast<char*>(As) + byte) = v;
    }
    __syncthreads();

    f32x4 acc[2][8];
#pragma unroll
    for (int rt = 0; rt < 2; ++rt)
#pragma unroll
        for (int t = 0; t < 8; ++t) acc[rt][t] = (f32x4){0.f, 0.f, 0.f, 0.f};

    const bf16_t* wb = W + (size_t)(wave * 8) * 24 * 512 + lane * 8;
    const int axor = (l16 & 7) << 4;    // (l16+16)&7 == l16&7

#pragma unroll 2
    for (int k = 0; k < 24; ++k) {
        int b0 = ((l16)      * 1536 + (k * 4 + quad) * 16) ^ axor;
        int b1 = ((l16 + 16) * 1536 + (k * 4 + quad) * 16) ^ axor;
        bf16x8 a0 = *reinterpret_cast<const bf16x8*>(
            reinterpret_cast<const char*>(As) + b0);
        bf16x8 a1 = *reinterpret_cast<const bf16x8*>(
            reinterpret_cast<const char*>(As) + b1);
#pragma unroll
        for (int t = 0; t < 8; ++t) {
            bf16x8 wv = *reinterpret_cast<const bf16x8*>(
                wb + (size_t)(t * 24 + k) * 512);
            acc[0][t] = MFMA16(a0, wv, acc[0][t]);
            acc[1][t] = MFMA16(a1, wv, acc[1][t]);
        }
    }

#pragma unroll
    for (int t = 0; t < 8; ++t) {
        float bv = bias[e0 + t * 16 + l16];
#pragma unroll
        for (int rt = 0; rt < 2; ++rt)
#pragma unroll
            for (int r = 0; r < 4; ++r) acc[rt][t][r] += bv;
    }

    float inv[2][4];
#pragma unroll
    for (int rt = 0; rt < 2; ++rt)
#pragma unroll
        for (int r = 0; r < 4; ++r) inv[rt][r] = 1.f;

    __shared__ float sq[4][32];
    if (seg <= 1) {
#pragma unroll
        for (int rt = 0; rt < 2; ++rt)
#pragma unroll
            for (int r = 0; r < 4; ++r) {
                float s = 0.f;
#pragma unroll
                for (int t = 0; t < 8; ++t) s += acc[rt][t][r] * acc[rt][t][r];
                s += __shfl_xor(s, 1);
                s += __shfl_xor(s, 2);
                s += __shfl_xor(s, 4);
                s += __shfl_xor(s, 8);
                if (l16 == 0) sq[wave][rt * 16 + quad * 4 + r] = s;
            }
        __syncthreads();
#pragma unroll
        for (int rt = 0; rt < 2; ++rt)
#pragma unroll
            for (int r = 0; r < 4; ++r) {
                int row = rt * 16 + quad * 4 + r;
                float tot = sq[0][row] + sq[1][row] + sq[2][row] + sq[3][row];
                inv[rt][r] = 1.0f / fmaxf(sqrtf(tot), 1e-12f);
            }
    }

#pragma unroll
    for (int rt = 0; rt < 2; ++rt)
#pragma unroll
        for (int r = 0; r < 4; ++r) {
            const int   R  = m0 + rt * 16 + quad * 4 + r;
            const float is = inv[rt][r];
            const size_t lin = (size_t)R * 512 + e0 + l16;
#pragma unroll
            for (int t = 0; t < 8; ++t)
                out[lin + t * 16] = acc[rt][t][r] * is;

            if (seg <= 1) {
                if (!PACKED) {
#pragma unroll
                    for (int t = 0; t < 8; ++t)
                        outb[lin + t * 16] = (bf16_t)(acc[rt][t][r] * is);
                } else {
                    size_t fb0; int elem, stride_c;
                    if (seg == 0) {
                        int qq = R / 196, vv = R - qq * 196;
                        fb0  = (size_t)qq * 224 + (vv >> 5) * 4;
                        elem = (((l16 >> 3) * 32 + (vv & 31)) << 3) | (l16 & 7);
                        stride_c = 28;
                    } else {
                        int bb = R >> 6;
                        fb0  = (size_t)bb * 64 + ((R >> 5) & 1) * 4;
                        elem = (((l16 >> 3) * 32 + (R & 31)) << 3) | (l16 & 7);
                        stride_c = 8;
                    }
#pragma unroll
                    for (int t = 0; t < 8; ++t) {
                        int c  = wave * 2 + (t >> 2);
                        int ks = t & 3;
                        outb[(fb0 + (size_t)c * stride_c + ks) * 512 + elem] =
                            (bf16_t)(acc[rt][t][r] * is);
                    }
                }
            }
        }
}

// ---------------------------------------------------------------------------
// MaxSim v13 = v9 + s_setprio(1) around the MFMA cluster (T5). The CU hosts
// 2 INDEPENDENT blocks (no cross-block barrier) generally at different chunk
// phases -> wave role diversity exists; prioritizing MFMA-phase waves keeps
// the matrix pipe fed through the other block's DMA/A-load bursts. No
// numeric change. (v9 baseline: 303-307 us, Occ 41%, Mfma ~36%.)
// Block = (q, b-pair), 8 waves = (vh = w>>2, bhat = (w>>1)&1, tt = w&1);
// acc = 4 x f32x16 = 64 acc-regs -> 4 waves/SIMD via __launch_bounds__(512,4).
// C/D map: col v = (vh*4+j)*32 + (lane&31),
// row t-in-tile = (reg&3) + 8*(reg>>2) + 4*(lane>>5), global t = tt*32+row.
// ---------------------------------------------------------------------------
__global__ __launch_bounds__(512, 4) void maxsim32p(
    const bf16_t* __restrict__ tp,  // [128][64][512] packed
    const bf16_t* __restrict__ vp,  // [128][224][512] packed
    float* __restrict__ sim)        // [128,128] (b major)
{
    const int tid  = threadIdx.x;
    const int wave = tid >> 6;
    const int lane = tid & 63;
    const int l32  = lane & 31;
    const int h    = lane >> 5;
    const int vh   = wave >> 2;             // 0: vt 0..3, 1: vt 4..6
    const int bhat = (wave >> 1) & 1;
    const int tt   = wave & 1;
    const int vt0  = vh * 4;

    const int n  = blockIdx.x;
    const int q  = n >> 6;
    const int bp = n & 63;
    const int b  = bp * 2 + bhat;

    __shared__ bf16_t vs[2][14336];         // 2 x 28 KiB (28 frags x 512)
    float* red = (float*)(void*)&vs[0][0];  // aliased after c=7 barrier

    f32x16 acc[4];                          // vh1 uses only 3
#pragma unroll
    for (int j = 0; j < 4; ++j)
#pragma unroll
        for (int r = 0; r < 16; ++r) acc[j][r] = 0.f;

    const bf16_t* vq = vp + (size_t)q * 114688;   // 224*512
    const bf16_t* tb = tp + (size_t)b * 32768;    // 64*512

    auto issue = [&](int buf, int c) {
#pragma unroll
        for (int g = 0; g < 4; ++g) {            // frags wave, wave+8, +16, +24
            int f = wave + g * 8;
            if (f < 28)
                gload_lds16(vq + (size_t)c * 14336 + f * 512 + lane * 8,
                            &vs[buf][f * 512]);
        }
    };

    issue(0, 0);
#pragma unroll
    for (int c = 0; c < 8; ++c) {
        __syncthreads();                          // buf c&1 DMA complete
        if (c < 7) issue((c + 1) & 1, c + 1);
        bf16x8 a[4];
        const bf16_t* ta = tb + (size_t)(c * 8 + tt * 4) * 512 + lane * 8;
#pragma unroll
        for (int ks = 0; ks < 4; ++ks)
            a[ks] = *reinterpret_cast<const bf16x8*>(ta + ks * 512);
        const bf16_t* bbase = &vs[c & 1][vt0 * 2048 + lane * 8];
        __builtin_amdgcn_s_setprio(1);            // T5: favor MFMA cluster
#pragma unroll
        for (int ks = 0; ks < 4; ++ks) {
#pragma unroll
            for (int j = 0; j < 3; ++j) {
                bf16x8 bv = *reinterpret_cast<const bf16x8*>(
                    bbase + (j * 4 + ks) * 512);
                acc[j] = MFMA32(a[ks], bv, acc[j]);
            }
            if (vh == 0) {                        // j=3 (vt3), uniform branch
                bf16x8 bv = *reinterpret_cast<const bf16x8*>(
                    bbase + (12 + ks) * 512);
                acc[3] = MFMA32(a[ks], bv, acc[3]);
            }
        }
        __builtin_amdgcn_s_setprio(0);
    }

    // ---- reductions. All waves passed the c=7 barrier (vs[0] dead). ----
#pragma unroll
    for (int reg = 0; reg < 16; ++reg) {
        float m = fmaxf(acc[0][reg], acc[1][reg]);
        if (vh == 0) {
            m = fmaxf(m, acc[2][reg]);
            m = fmaxf(m, acc[3][reg]);
        } else if (l32 < 4) {
            m = fmaxf(m, acc[2][reg]);            // vt6: cols 192..195 valid
        }
        m = fmaxf(m, __shfl_xor(m, 1));
        m = fmaxf(m, __shfl_xor(m, 2));
        m = fmaxf(m, __shfl_xor(m, 4));
        m = fmaxf(m, __shfl_xor(m, 8));
        m = fmaxf(m, __shfl_xor(m, 16));
        if (l32 == 0) {
            int row = tt * 32 + (reg & 3) + 8 * (reg >> 2) + 4 * h;
            red[(bhat * 2 + vh) * 64 + row] = m;
        }
    }
#pragma unroll
    for (int j = 0; j < 3; ++j) {
        float m = acc[j][0];
#pragma unroll
        for (int reg = 1; reg < 16; ++reg) m = fmaxf(m, acc[j][reg]);
        m = fmaxf(m, __shfl_xor(m, 32));          // combine h halves
        if (h == 0) red[256 + (bhat * 2 + tt) * 224 + (vt0 + j) * 32 + l32] = m;
    }
    if (vh == 0) {                                // j=3 (vt3)
        float m = acc[3][0];
#pragma unroll
        for (int reg = 1; reg < 16; ++reg) m = fmaxf(m, acc[3][reg]);
        m = fmaxf(m, __shfl_xor(m, 32));
        if (h == 0) red[256 + (bhat * 2 + tt) * 224 + 3 * 32 + l32] = m;
    }
    __syncthreads();

    if (wave == 0) {
#pragma unroll
        for (int bi = 0; bi < 2; ++bi) {
            float t = fmaxf(red[(bi * 2 + 0) * 64 + lane],
                            red[(bi * 2 + 1) * 64 + lane]);
            float cc = 0.f;
            for (int v = lane; v < 196; v += 64)
                cc += fmaxf(red[256 + (bi * 2 + 0) * 224 + v],
                            red[256 + (bi * 2 + 1) * 224 + v]);
#pragma unroll
            for (int mk = 1; mk <= 32; mk <<= 1) {
                t  += __shfl_xor(t, mk);
                cc += __shfl_xor(cc, mk);
            }
            if (lane == 0)
                sim[(size_t)(bp * 2 + bi) * 128 + q] =
                    0.5f * (t * (1.0f / 196.0f) + cc * (1.0f / 64.0f));
        }
    }
}

// ---------------------------------------------------------------------------
// MaxSim v5 (legacy linear-mirror path, tier-1 ws fallback) — unchanged.
// ---------------------------------------------------------------------------
__global__ __launch_bounds__(256) void maxsim32(
    const bf16_t* __restrict__ te,  // [128,64,512]
    const bf16_t* __restrict__ ve,  // [128,196,512]
    float* __restrict__ sim)        // [128,128] (b major)
{
    const int tid  = threadIdx.x;
    const int wave = tid >> 6;
    const int lane = tid & 63;
    const int l32  = lane & 31;
    const int h    = lane >> 5;
    const int bhat = wave >> 1;
    const int tt   = wave & 1;

    const int n  = blockIdx.x;
    const int q  = n >> 6;
    const int bp = n & 63;
    const int b  = bp * 2 + bhat;

    __shared__ bf16_t vs[2][224 * 64];
    __shared__ float  tmax_s[2][64];
    __shared__ float  vmax_s[2][2][224];

    f32x16 acc[7];
#pragma unroll
    for (int vt = 0; vt < 7; ++vt)
#pragma unroll
        for (int r = 0; r < 16; ++r) acc[vt][r] = 0.f;

    auto issue = [&](int buf, int c) {
        for (int g = wave; g < 28; g += 4) {
            int r   = g * 8 + (lane >> 3);
            int sr  = r < 196 ? r : 195;
            int seg = (lane & 7) ^ (lane >> 3);
            gload_lds16(ve + ((size_t)q * 196 + sr) * 512 + c * 64 + seg * 8,
                        &vs[buf][g * 512]);
        }
    };

    const size_t tbase = ((size_t)b * 64 + tt * 32 + l32) * 512;

    issue(0, 0);
#pragma unroll
    for (int c = 0; c < 8; ++c) {
        __syncthreads();
        if (c < 7) issue((c + 1) & 1, c + 1);
        bf16x8 a[4];
#pragma unroll
        for (int ks = 0; ks < 4; ++ks)
            a[ks] = *reinterpret_cast<const bf16x8*>(
                te + tbase + c * 64 + ks * 16 + h * 8);
        const int buf = c & 1;
#pragma unroll
        for (int ks = 0; ks < 4; ++ks)
#pragma unroll
            for (int vt = 0; vt < 7; ++vt) {
                int row  = vt * 32 + l32;
                int phys = (ks * 2 + h) ^ (row & 7);
                bf16x8 bv = *reinterpret_cast<const bf16x8*>(
                    &vs[buf][row * 64 + phys * 8]);
                acc[vt] = MFMA32(a[ks], bv, acc[vt]);
            }
    }

#pragma unroll
    for (int reg = 0; reg < 16; ++reg) {
        float m = acc[0][reg];
#pragma unroll
        for (int vt = 1; vt < 6; ++vt) m = fmaxf(m, acc[vt][reg]);
        if (l32 < 4) m = fmaxf(m, acc[6][reg]);
        m = fmaxf(m, __shfl_xor(m, 1));
        m = fmaxf(m, __shfl_xor(m, 2));
        m = fmaxf(m, __shfl_xor(m, 4));
        m = fmaxf(m, __shfl_xor(m, 8));
        m = fmaxf(m, __shfl_xor(m, 16));
        if (l32 == 0) {
            int row = tt * 32 + (reg & 3) + 8 * (reg >> 2) + 4 * h;
            tmax_s[bhat][row] = m;
        }
    }
#pragma unroll
    for (int vt = 0; vt < 7; ++vt) {
        float m = acc[vt][0];
#pragma unroll
        for (int reg = 1; reg < 16; ++reg) m = fmaxf(m, acc[vt][reg]);
        m = fmaxf(m, __shfl_xor(m, 32));
        if (h == 0) vmax_s[bhat][tt][vt * 32 + l32] = m;
    }
    __syncthreads();

    if (wave == 0) {
        float t0 = tmax_s[0][lane];
        float t1 = tmax_s[1][lane];
        float c0 = 0.f, c1 = 0.f;
        for (int v = lane; v < 196; v += 64) {
            c0 += fmaxf(vmax_s[0][0][v], vmax_s[0][1][v]);
            c1 += fmaxf(vmax_s[1][0][v], vmax_s[1][1][v]);
        }
#pragma unroll
        for (int mk = 1; mk <= 32; mk <<= 1) {
            t0 += __shfl_xor(t0, mk);
            t1 += __shfl_xor(t1, mk);
            c0 += __shfl_xor(c0, mk);
            c1 += __shfl_xor(c1, mk);
        }
        if (lane == 0) {
            sim[(size_t)(bp * 2 + 0) * 128 + q] = 0.5f * (t0 * (1.0f / 196.0f) + c0 * (1.0f / 64.0f));
            sim[(size_t)(bp * 2 + 1) * 128 + q] = 0.5f * (t1 * (1.0f / 196.0f) + c1 * (1.0f / 64.0f));
        }
    }
}

// ---------------------------------------------------------------------------
// Fallback projection (f32 weights, 16-row blocks) — used only if ws too small
// ---------------------------------------------------------------------------
__global__ __launch_bounds__(256) void proj_fb(
    const float* __restrict__ A, const float* __restrict__ Wf,
    const float* __restrict__ bias, float* __restrict__ out, int do_l2)
{
    const int tid  = threadIdx.x;
    const int wave = tid >> 6;
    const int lane = tid & 63;
    const int l16  = lane & 15;
    const int quad = lane >> 4;
    const int m0   = blockIdx.x * 16;
    const int e0   = wave * 128;

    f32x4 acc[8];
#pragma unroll
    for (int t = 0; t < 8; ++t) acc[t] = (f32x4){0.f, 0.f, 0.f, 0.f};
    const float* arow = A + (size_t)(m0 + l16) * 768 + quad * 8;
    for (int k0 = 0; k0 < 768; k0 += 32) {
        bf16x8 af = cvt8(arow + k0);
#pragma unroll
        for (int t = 0; t < 8; ++t) {
            bf16x8 wv = cvt8(Wf + (size_t)(e0 + t * 16 + l16) * 768 + quad * 8 + k0);
            acc[t] = MFMA16(af, wv, acc[t]);
        }
    }
#pragma unroll
    for (int t = 0; t < 8; ++t) {
        float bv = bias[e0 + t * 16 + l16];
#pragma unroll
        for (int r = 0; r < 4; ++r) acc[t][r] += bv;
    }
    float inv[4] = {1.f, 1.f, 1.f, 1.f};
    __shared__ float sq[4][16];
    if (do_l2) {
#pragma unroll
        for (int r = 0; r < 4; ++r) {
            float s = 0.f;
#pragma unroll
            for (int t = 0; t < 8; ++t) s += acc[t][r] * acc[t][r];
            s += __shfl_xor(s, 1); s += __shfl_xor(s, 2);
            s += __shfl_xor(s, 4); s += __shfl_xor(s, 8);
            if (l16 == 0) sq[wave][quad * 4 + r] = s;
        }
        __syncthreads();
#pragma unroll
        for (int r = 0; r < 4; ++r) {
            float tot = sq[0][quad * 4 + r] + sq[1][quad * 4 + r]
                      + sq[2][quad * 4 + r] + sq[3][quad * 4 + r];
            inv[r] = 1.0f / fmaxf(sqrtf(tot), 1e-12f);
        }
    }
#pragma unroll
    for (int t = 0; t < 8; ++t)
#pragma unroll
        for (int r = 0; r < 4; ++r)
            out[(size_t)(m0 + quad * 4 + r) * 512 + (e0 + t * 16 + l16)] =
                acc[t][r] * inv[r];
}

// ---------------------------------------------------------------------------
// Fallback maxsim (f32 operands from d_out, 16x16 path) — ws-too-small only
// ---------------------------------------------------------------------------
__global__ __launch_bounds__(256) void maxsim_fb(
    const float* __restrict__ te, const float* __restrict__ ve,
    float* __restrict__ sim)
{
    const int tid  = threadIdx.x;
    const int wave = tid >> 6;
    const int lane = tid & 63;
    const int l16  = lane & 15;
    const int quad = lane >> 4;
    const int q    = blockIdx.x >> 6;
    const int bp   = blockIdx.x & 63;

    __shared__ bf16_t vsl[208 * 72];
    __shared__ float  maxt_s[2][4][208];
    __shared__ float  t2v_part[2][4];

    f32x4 acc0[13], acc1[13];
#pragma unroll
    for (int vt = 0; vt < 13; ++vt) {
        acc0[vt] = (f32x4){0.f, 0.f, 0.f, 0.f};
        acc1[vt] = (f32x4){0.f, 0.f, 0.f, 0.f};
    }
    const size_t toff0 = ((size_t)(bp * 2) * 64 + wave * 16 + l16) * 512 + quad * 8;
    const size_t toff1 = toff0 + (size_t)64 * 512;

    for (int k0 = 0; k0 < 512; k0 += 64) {
        __syncthreads();
        for (int s = tid; s < 416; s += 256) {
            const int row  = s >> 1;
            const int half = s & 1;
            const int vsrc = row < 196 ? row : 195;
            bf16x8 tmp[4];
            const size_t goff = ((size_t)q * 196 + vsrc) * 512 + k0 + half * 32;
#pragma unroll
            for (int j = 0; j < 4; ++j) tmp[j] = cvt8(ve + goff + j * 8);
            bf16_t* dst = &vsl[row * 72 + half * 32];
#pragma unroll
            for (int j = 0; j < 4; ++j)
                *reinterpret_cast<bf16x8*>(dst + j * 8) = tmp[j];
        }
        __syncthreads();
#pragma unroll
        for (int ks = 0; ks < 2; ++ks) {
            bf16x8 a0 = cvt8(te + toff0 + k0 + ks * 32);
            bf16x8 a1 = cvt8(te + toff1 + k0 + ks * 32);
#pragma unroll
            for (int vt = 0; vt < 13; ++vt) {
                bf16x8 bv = *reinterpret_cast<const bf16x8*>(
                    &vsl[(vt * 16 + l16) * 72 + ks * 32 + quad * 8]);
                acc0[vt] = MFMA16(a0, bv, acc0[vt]);
                acc1[vt] = MFMA16(a1, bv, acc1[vt]);
            }
        }
    }
#pragma unroll
    for (int bi = 0; bi < 2; ++bi) {
        const f32x4* acc = bi ? acc1 : acc0;
        float sum_maxv = 0.f;
#pragma unroll
        for (int r = 0; r < 4; ++r) {
            float m = -3.0e38f;
#pragma unroll
            for (int vt = 0; vt < 13; ++vt) {
                int v = vt * 16 + l16;
                if (v < 196) m = fmaxf(m, acc[vt][r]);
            }
            m = fmaxf(m, __shfl_xor(m, 1));
            m = fmaxf(m, __shfl_xor(m, 2));
            m = fmaxf(m, __shfl_xor(m, 4));
            m = fmaxf(m, __shfl_xor(m, 8));
            sum_maxv += m;
        }
        sum_maxv += __shfl_xor(sum_maxv, 16);
        sum_maxv += __shfl_xor(sum_maxv, 32);
        if (lane == 0) t2v_part[bi][wave] = sum_maxv;
#pragma unroll
        for (int vt = 0; vt < 13; ++vt) {
            float m = fmaxf(fmaxf(acc[vt][0], acc[vt][1]),
                            fmaxf(acc[vt][2], acc[vt][3]));
            m = fmaxf(m, __shfl_xor(m, 16));
            m = fmaxf(m, __shfl_xor(m, 32));
            if (lane < 16) maxt_s[bi][wave][vt * 16 + l16] = m;
        }
    }
    __syncthreads();
    if (wave == 0) {
#pragma unroll
        for (int bi = 0; bi < 2; ++bi) {
            float s_row = t2v_part[bi][0] + t2v_part[bi][1]
                        + t2v_part[bi][2] + t2v_part[bi][3];
            float s_col = 0.f;
            for (int v = lane; v < 196; v += 64) {
                float m = fmaxf(fmaxf(maxt_s[bi][0][v], maxt_s[bi][1][v]),
                                fmaxf(maxt_s[bi][2][v], maxt_s[bi][3][v]));
                s_col += m;
            }
            s_col += __shfl_xor(s_col, 1);
            s_col += __shfl_xor(s_col, 2);
            s_col += __shfl_xor(s_col, 4);
            s_col += __shfl_xor(s_col, 8);
            s_col += __shfl_xor(s_col, 16);
            s_col += __shfl_xor(s_col, 32);
            if (lane == 0)
                sim[(size_t)(bp * 2 + bi) * 128 + q] =
                    0.5f * (s_row * (1.0f / 196.0f) + s_col * (1.0f / 64.0f));
        }
    }
}

// ---------------------------------------------------------------------------
// text_mask[b,t] = (t < len[b]); int64-vs-int32 auto-detect (lengths 1..64).
// ---------------------------------------------------------------------------
__global__ void mask_kernel(const int* __restrict__ len, float* __restrict__ mask)
{
    int i = blockIdx.x * 256 + threadIdx.x;
    int is64 = (len[1] == 0) ? 1 : 0;
    if (i < 128 * 64) {
        int b = i >> 6;
        int t = i & 63;
        int L = is64 ? len[2 * b] : len[b];
        mask[i] = (t < L) ? 1.0f : 0.0f;
    }
}

extern "C" void kernel_launch(void* const* d_in, const int* in_sizes, int n_in,
                              void* d_out, int out_size, void* d_ws, size_t ws_size,
                              hipStream_t stream)
{
    int idx[13] = {0, 1, 2, 3, 4, 5, 6, 7, 8, 9, 10, 11, 12};
    if (in_sizes && n_in >= 13) {
        bool dict = (in_sizes[2] == 19267584) && (in_sizes[4] == 393216);
        if (!dict) {
            static const int alpha_sizes[13] = {393216, 393216, 393216, 393216,
                                                512, 512, 512, 512, 128,
                                                98304, 6291456, 98304, 19267584};
            bool alpha = true;
            for (int i = 0; i < 13; ++i)
                if (in_sizes[i] != alpha_sizes[i]) { alpha = false; break; }
            if (alpha) {
                const int m[13] = {11, 9, 12, 10, 2, 6, 0, 4, 3, 7, 1, 5, 8};
                for (int i = 0; i < 13; ++i) idx[i] = m[i];
            }
        }
    }

    const float* visual_cls     = (const float*)d_in[idx[0]];
    const float* textual_cls    = (const float*)d_in[idx[1]];
    const float* visual_tokens  = (const float*)d_in[idx[2]];
    const float* textual_tokens = (const float*)d_in[idx[3]];
    const float* Wv_cls = (const float*)d_in[idx[4]];
    const float* bv_cls = (const float*)d_in[idx[5]];
    const float* Wt_cls = (const float*)d_in[idx[6]];
    const float* bt_cls = (const float*)d_in[idx[7]];
    const float* Wv_tok = (const float*)d_in[idx[8]];
    const float* bv_tok = (const float*)d_in[idx[9]];
    const float* Wt_tok = (const float*)d_in[idx[10]];
    const float* bt_tok = (const float*)d_in[idx[11]];
    const int*   text_length = (const int*)d_in[idx[12]];

    float* out    = (float*)d_out;
    float* o_vcls = out;
    float* o_tcls = out + 65536;
    float* o_ve   = out + 131072;
    float* o_te   = out + 12976128;
    float* o_mask = out + 17170432;
    float* o_sim  = out + 17178624;

    const size_t NVE = 12845056;   // linear bf16 ve mirror (tier-1)
    const size_t NTE = 4194304;
    const size_t need_new = (4 * (size_t)WN + VP_ELEMS + TP_ELEMS) * 2;   // 40.9 MB
    const size_t need_old = (4 * (size_t)WN + NVE + NTE) * 2;             // 37.2 MB

    dim3 blk(256);
    if (ws_size >= need_new) {
        bf16_t* w_all = (bf16_t*)d_ws;
        bf16_t* vp    = w_all + 4 * (size_t)WN;
        bf16_t* tp    = vp + VP_ELEMS;
        cvt_w4<<<768, blk, 0, stream>>>(Wv_cls, Wt_cls, Wv_tok, Wt_tok, w_all);
        zero_tail<<<1024, blk, 0, stream>>>(vp);
        proj_all<1><<<1048, blk, 0, stream>>>(visual_tokens, textual_tokens,
                                              visual_cls, textual_cls, w_all,
                                              bv_cls, bt_cls, bv_tok, bt_tok,
                                              out, vp, tp);
        mask_kernel<<<32, blk, 0, stream>>>(text_length, o_mask);
        maxsim32p<<<128 * 64, dim3(512), 0, stream>>>(tp, vp, o_sim);
    } else if (ws_size >= need_old) {
        bf16_t* w_all = (bf16_t*)d_ws;
        bf16_t* b_ve  = w_all + 4 * (size_t)WN;
        bf16_t* b_te  = b_ve + NVE;
        cvt_w4<<<768, blk, 0, stream>>>(Wv_cls, Wt_cls, Wv_tok, Wt_tok, w_all);
        proj_all<0><<<1048, blk, 0, stream>>>(visual_tokens, textual_tokens,
                                              visual_cls, textual_cls, w_all,
                                              bv_cls, bt_cls, bv_tok, bt_tok,
                                              out, b_ve, b_te);
        mask_kernel<<<32, blk, 0, stream>>>(text_length, o_mask);
        maxsim32<<<128 * 64, blk, 0, stream>>>(b_te, b_ve, o_sim);
    } else {
        proj_fb<<<8,    blk, 0, stream>>>(visual_cls,     Wv_cls, bv_cls, o_vcls, 0);
        proj_fb<<<8,    blk, 0, stream>>>(textual_cls,    Wt_cls, bt_cls, o_tcls, 0);
        proj_fb<<<1568, blk, 0, stream>>>(visual_tokens,  Wv_tok, bv_tok, o_ve, 1);
        proj_fb<<<512,  blk, 0, stream>>>(textual_tokens, Wt_tok, bt_tok, o_te, 1);
        mask_kernel<<<32, blk, 0, stream>>>(text_length, o_mask);
        maxsim_fb<<<128 * 64, blk, 0, stream>>>(o_te, o_ve, o_sim);
    }
}

// Round 13
// 497.273 us; speedup vs baseline: 1.0373x; 1.0271x over previous
//
#include <hip/hip_runtime.h>
#include <hip/hip_bf16.h>

typedef __bf16 bf16_t;
typedef __bf16 bf16x8 __attribute__((ext_vector_type(8)));
typedef __bf16 bf16x4 __attribute__((ext_vector_type(4)));
typedef float f32x4 __attribute__((ext_vector_type(4)));
typedef float f32x16 __attribute__((ext_vector_type(16)));

#define MFMA16(a, b, c) __builtin_amdgcn_mfma_f32_16x16x32_bf16((a), (b), (c), 0, 0, 0)
#define MFMA32(a, b, c) __builtin_amdgcn_mfma_f32_32x32x16_bf16((a), (b), (c), 0, 0, 0)

#define WN 393216  // elems per weight matrix (512*768)
#define VP_ELEMS 14680064ULL   // 128 q * 224 frags * 512
#define TP_ELEMS 4194304ULL    // 128 b * 64 frags * 512

// load 8 consecutive f32, round to bf16x8 (RNE)
__device__ inline bf16x8 cvt8(const float* __restrict__ p) {
    f32x4 a = *reinterpret_cast<const f32x4*>(p);
    f32x4 b = *reinterpret_cast<const f32x4*>(p + 4);
    bf16x8 r;
    r[0] = (bf16_t)a[0]; r[1] = (bf16_t)a[1]; r[2] = (bf16_t)a[2]; r[3] = (bf16_t)a[3];
    r[4] = (bf16_t)b[0]; r[5] = (bf16_t)b[1]; r[6] = (bf16_t)b[2]; r[7] = (bf16_t)b[3];
    return r;
}

// async global->LDS DMA, 16 B/lane; LDS dest = wave-uniform base + lane*16
__device__ __forceinline__ void gload_lds16(const bf16_t* g, bf16_t* l) {
    __builtin_amdgcn_global_load_lds(
        (const __attribute__((address_space(1))) void*)g,
        (__attribute__((address_space(3))) void*)l, 16, 0, 0);
}

// ---------------------------------------------------------------------------
// Fused prep kernel (tier-0): cvt_w4 + zero_tail + mask in 1 launch.
//   blocks [0, 768)      : W f32 -> bf16, packed in MFMA-fragment order
//     P[seg][(ec*8 + t)*24 + k][lane][j]
//       <- W[seg][ec*128 + t*16 + (lane&15)][k*32 + (lane>>4)*8 + j]
//   blocks [768, 1792)   : zero vt=6 tail frags of the ve pack
//   blocks [1792, 1824)  : text_mask
// All three ranges are mutually independent and precede proj_all.
// ---------------------------------------------------------------------------
__global__ __launch_bounds__(256) void prep_all(
    const float* __restrict__ s0, const float* __restrict__ s1,
    const float* __restrict__ s2, const float* __restrict__ s3,
    bf16_t* __restrict__ d,       // packed w_all
    bf16_t* __restrict__ vp,      // ve pack (tail zeroing)
    const int* __restrict__ len, float* __restrict__ mask)
{
    const int blk = blockIdx.x;
    if (blk < 768) {
        int g = blk * 256 + threadIdx.x;          // 8-elem group, < 196608
        int seg = g / 49152;                      // WN/8
        int rem = g - seg * 49152;
        int frag = rem >> 6;                      // (ec*8+t)*24 + k, 0..767
        int lane = rem & 63;
        int k  = frag % 24;
        int et = frag / 24;                       // ec*8 + t, 0..31
        int row = et * 16 + (lane & 15);
        int col = k * 32 + (lane >> 4) * 8;
        const float* s = (seg == 0) ? s0 : (seg == 1) ? s1 : (seg == 2) ? s2 : s3;
        bf16x8 r = cvt8(s + (size_t)row * 768 + col);
        *reinterpret_cast<bf16x8*>(d + (size_t)g * 8) = r;
    } else if (blk < 1792) {
        int i = (blk - 768) * 256 + threadIdx.x;  // bf16x8 store idx, < 262144
        int off = (i & 63) * 8;
        int ks  = (i >> 6) & 3;
        int c   = (i >> 8) & 7;
        int q   = i >> 11;
        size_t addr = ((size_t)q * 224 + c * 28 + 24 + ks) * 512 + off;
        *reinterpret_cast<f32x4*>(vp + addr) = (f32x4){0.f, 0.f, 0.f, 0.f};
    } else {
        int i = (blk - 1792) * 256 + threadIdx.x;
        int is64 = (len[1] == 0) ? 1 : 0;
        if (i < 128 * 64) {
            int b = i >> 6;
            int t = i & 63;
            int L = is64 ? len[2 * b] : len[b];
            mask[i] = (t < L) ? 1.0f : 0.0f;
        }
    }
}

// ---------------------------------------------------------------------------
// cvt_w4 standalone (tier-1 path): same packed layout as prep_all range 0.
// ---------------------------------------------------------------------------
__global__ __launch_bounds__(256) void cvt_w4(
    const float* __restrict__ s0, const float* __restrict__ s1,
    const float* __restrict__ s2, const float* __restrict__ s3,
    bf16_t* __restrict__ d)
{
    int g = blockIdx.x * 256 + threadIdx.x;   // 8-elem group, < 196608
    int seg = g / 49152;                      // WN/8
    int rem = g - seg * 49152;
    int frag = rem >> 6;                      // (ec*8+t)*24 + k, 0..767
    int lane = rem & 63;
    int k  = frag % 24;
    int et = frag / 24;                       // ec*8 + t, 0..31
    int row = et * 16 + (lane & 15);          // = ec*128 + t*16 + l16
    int col = k * 32 + (lane >> 4) * 8;
    const float* s = (seg == 0) ? s0 : (seg == 1) ? s1 : (seg == 2) ? s2 : s3;
    bf16x8 r = cvt8(s + (size_t)row * 768 + col);
    *reinterpret_cast<bf16x8*>(d + (size_t)g * 8) = r;
}

// ---------------------------------------------------------------------------
// Merged projection v2 (R7 structure): W fragment-packed reads + A staged
// once in LDS bf16 (XOR-swizzled). k-loop unroll 2. Bit-identical outputs.
// ---------------------------------------------------------------------------
template<int PACKED>
__global__ __launch_bounds__(256, 2) void proj_all(
    const float* __restrict__ vtok, const float* __restrict__ ttok,
    const float* __restrict__ vcls, const float* __restrict__ tcls,
    const bf16_t* __restrict__ w_all,   // packed [4][768 frags][512]
    const float* __restrict__ bvc, const float* __restrict__ btc,
    const float* __restrict__ bvt, const float* __restrict__ btt,
    float* __restrict__ out_base,       // d_out f32
    bf16_t* __restrict__ bve, bf16_t* __restrict__ bte)
{
    const int tid  = threadIdx.x;
    const int wave = tid >> 6;          // = ec (e-slice 128*wave)
    const int lane = tid & 63;
    const int l16  = lane & 15;
    const int quad = lane >> 4;
    const int e0   = wave * 128;
    const int id   = blockIdx.x;

    const float* A; const bf16_t* W; const float* bias;
    float* out; bf16_t* outb; int seg, m0;
    if (id < 784)       { seg = 0; A = vtok; W = w_all + 2 * WN; bias = bvt;
                          out = out_base + 131072;   outb = bve; m0 = id * 32; }
    else if (id < 1040) { seg = 1; A = ttok; W = w_all + 3 * WN; bias = btt;
                          out = out_base + 12976128; outb = bte; m0 = (id - 784) * 32; }
    else if (id < 1044) { seg = 2; A = vcls; W = w_all;          bias = bvc;
                          out = out_base;             outb = nullptr; m0 = (id - 1040) * 32; }
    else                { seg = 3; A = tcls; W = w_all + WN;     bias = btc;
                          out = out_base + 65536;     outb = nullptr; m0 = (id - 1044) * 32; }

    // ---- stage A tile (32 rows x 768) to LDS bf16, XOR-swizzled ----
    __shared__ bf16_t As[32 * 768];     // 48 KiB
#pragma unroll
    for (int it = 0; it < 12; ++it) {
        int idx = it * 256 + tid;       // 16B-granule id, < 3072
        int row = idx / 96;
        int cg  = idx - row * 96;
        bf16x8 v = cvt8(A + (size_t)(m0 + row) * 768 + cg * 8);
        int byte = (row * 1536 + cg * 16) ^ ((row & 7) << 4);
        *reinterpret_cast<bf16x8*>(reinterpret_cast<char*>(As) + byte) = v;
    }
    __syncthreads();

    f32x4 acc[2][8];
#pragma unroll
    for (int rt = 0; rt < 2; ++rt)
#pragma unroll
        for (int t = 0; t < 8; ++t) acc[rt][t] = (f32x4){0.f, 0.f, 0.f, 0.f};

    const bf16_t* wb = W + (size_t)(wave * 8) * 24 * 512 + lane * 8;
    const int axor = (l16 & 7) << 4;    // (l16+16)&7 == l16&7

#pragma unroll 2
    for (int k = 0; k < 24; ++k) {
        int b0 = ((l16)      * 1536 + (k * 4 + quad) * 16) ^ axor;
        int b1 = ((l16 + 16) * 1536 + (k * 4 + quad) * 16) ^ axor;
        bf16x8 a0 = *reinterpret_cast<const bf16x8*>(
            reinterpret_cast<const char*>(As) + b0);
        bf16x8 a1 = *reinterpret_cast<const bf16x8*>(
            reinterpret_cast<const char*>(As) + b1);
#pragma unroll
        for (int t = 0; t < 8; ++t) {
            bf16x8 wv = *reinterpret_cast<const bf16x8*>(
                wb + (size_t)(t * 24 + k) * 512);
            acc[0][t] = MFMA16(a0, wv, acc[0][t]);
            acc[1][t] = MFMA16(a1, wv, acc[1][t]);
        }
    }

#pragma unroll
    for (int t = 0; t < 8; ++t) {
        float bv = bias[e0 + t * 16 + l16];
#pragma unroll
        for (int rt = 0; rt < 2; ++rt)
#pragma unroll
            for (int r = 0; r < 4; ++r) acc[rt][t][r] += bv;
    }

    float inv[2][4];
#pragma unroll
    for (int rt = 0; rt < 2; ++rt)
#pragma unroll
        for (int r = 0; r < 4; ++r) inv[rt][r] = 1.f;

    __shared__ float sq[4][32];
    if (seg <= 1) {
#pragma unroll
        for (int rt = 0; rt < 2; ++rt)
#pragma unroll
            for (int r = 0; r < 4; ++r) {
                float s = 0.f;
#pragma unroll
                for (int t = 0; t < 8; ++t) s += acc[rt][t][r] * acc[rt][t][r];
                s += __shfl_xor(s, 1);
                s += __shfl_xor(s, 2);
                s += __shfl_xor(s, 4);
                s += __shfl_xor(s, 8);
                if (l16 == 0) sq[wave][rt * 16 + quad * 4 + r] = s;
            }
        __syncthreads();
#pragma unroll
        for (int rt = 0; rt < 2; ++rt)
#pragma unroll
            for (int r = 0; r < 4; ++r) {
                int row = rt * 16 + quad * 4 + r;
                float tot = sq[0][row] + sq[1][row] + sq[2][row] + sq[3][row];
                inv[rt][r] = 1.0f / fmaxf(sqrtf(tot), 1e-12f);
            }
    }

#pragma unroll
    for (int rt = 0; rt < 2; ++rt)
#pragma unroll
        for (int r = 0; r < 4; ++r) {
            const int   R  = m0 + rt * 16 + quad * 4 + r;
            const float is = inv[rt][r];
            const size_t lin = (size_t)R * 512 + e0 + l16;
#pragma unroll
            for (int t = 0; t < 8; ++t)
                out[lin + t * 16] = acc[rt][t][r] * is;

            if (seg <= 1) {
                if (!PACKED) {
#pragma unroll
                    for (int t = 0; t < 8; ++t)
                        outb[lin + t * 16] = (bf16_t)(acc[rt][t][r] * is);
                } else {
                    size_t fb0; int elem, stride_c;
                    if (seg == 0) {
                        int qq = R / 196, vv = R - qq * 196;
                        fb0  = (size_t)qq * 224 + (vv >> 5) * 4;
                        elem = (((l16 >> 3) * 32 + (vv & 31)) << 3) | (l16 & 7);
                        stride_c = 28;
                    } else {
                        int bb = R >> 6;
                        fb0  = (size_t)bb * 64 + ((R >> 5) & 1) * 4;
                        elem = (((l16 >> 3) * 32 + (R & 31)) << 3) | (l16 & 7);
                        stride_c = 8;
                    }
#pragma unroll
                    for (int t = 0; t < 8; ++t) {
                        int c  = wave * 2 + (t >> 2);
                        int ks = t & 3;
                        outb[(fb0 + (size_t)c * stride_c + ks) * 512 + elem] =
                            (bf16_t)(acc[rt][t][r] * is);
                    }
                }
            }
        }
}

// ---------------------------------------------------------------------------
// MaxSim v14 = v9 + setprio (null, kept) + A-load prefetch: a[] for chunk
// c+1 is loaded AFTER compute of chunk c (same registers, after last use).
// The loads' L2 latency (~200-400 cyc) drains inside the next barrier's
// existing vmcnt(0) wait instead of sitting serially between barrier-exit
// and the first MFMA. Same register budget and accumulation order as v9
// -> bit-identical sim. (v9 baseline: 303-307 us, Occ 41%, Mfma ~36%.)
// Block = (q, b-pair), 8 waves = (vh = w>>2, bhat = (w>>1)&1, tt = w&1);
// acc = 4 x f32x16 = 64 acc-regs -> 4 waves/SIMD via __launch_bounds__(512,4).
// C/D map: col v = (vh*4+j)*32 + (lane&31),
// row t-in-tile = (reg&3) + 8*(reg>>2) + 4*(lane>>5), global t = tt*32+row.
// ---------------------------------------------------------------------------
__global__ __launch_bounds__(512, 4) void maxsim32p(
    const bf16_t* __restrict__ tp,  // [128][64][512] packed
    const bf16_t* __restrict__ vp,  // [128][224][512] packed
    float* __restrict__ sim)        // [128,128] (b major)
{
    const int tid  = threadIdx.x;
    const int wave = tid >> 6;
    const int lane = tid & 63;
    const int l32  = lane & 31;
    const int h    = lane >> 5;
    const int vh   = wave >> 2;             // 0: vt 0..3, 1: vt 4..6
    const int bhat = (wave >> 1) & 1;
    const int tt   = wave & 1;
    const int vt0  = vh * 4;

    const int n  = blockIdx.x;
    const int q  = n >> 6;
    const int bp = n & 63;
    const int b  = bp * 2 + bhat;

    __shared__ bf16_t vs[2][14336];         // 2 x 28 KiB (28 frags x 512)
    float* red = (float*)(void*)&vs[0][0];  // aliased after c=7 barrier

    f32x16 acc[4];                          // vh1 uses only 3
#pragma unroll
    for (int j = 0; j < 4; ++j)
#pragma unroll
        for (int r = 0; r < 16; ++r) acc[j][r] = 0.f;

    const bf16_t* vq = vp + (size_t)q * 114688;            // 224*512
    const bf16_t* tb = tp + (size_t)b * 32768 + (size_t)(tt * 4) * 512 + lane * 8;

    auto issue = [&](int buf, int c) {
#pragma unroll
        for (int g = 0; g < 4; ++g) {            // frags wave, wave+8, +16, +24
            int f = wave + g * 8;
            if (f < 28)
                gload_lds16(vq + (size_t)c * 14336 + f * 512 + lane * 8,
                            &vs[buf][f * 512]);
        }
    };

    issue(0, 0);
    bf16x8 a[4];                                // A frags for the CURRENT chunk
#pragma unroll
    for (int ks = 0; ks < 4; ++ks)
        a[ks] = *reinterpret_cast<const bf16x8*>(tb + ks * 512);

#pragma unroll
    for (int c = 0; c < 8; ++c) {
        __syncthreads();                        // drains chunk-c DMA AND a[] loads
        if (c < 7) issue((c + 1) & 1, c + 1);
        const bf16_t* bbase = &vs[c & 1][vt0 * 2048 + lane * 8];
        __builtin_amdgcn_s_setprio(1);          // T5 (neutral, kept)
#pragma unroll
        for (int ks = 0; ks < 4; ++ks) {
#pragma unroll
            for (int j = 0; j < 3; ++j) {
                bf16x8 bv = *reinterpret_cast<const bf16x8*>(
                    bbase + (j * 4 + ks) * 512);
                acc[j] = MFMA32(a[ks], bv, acc[j]);
            }
            if (vh == 0) {                      // j=3 (vt3), uniform branch
                bf16x8 bv = *reinterpret_cast<const bf16x8*>(
                    bbase + (12 + ks) * 512);
                acc[3] = MFMA32(a[ks], bv, acc[3]);
            }
        }
        __builtin_amdgcn_s_setprio(0);
        if (c < 7) {                            // prefetch A for chunk c+1
            const bf16_t* ta = tb + (size_t)((c + 1) * 8) * 512;
#pragma unroll
            for (int ks = 0; ks < 4; ++ks)
                a[ks] = *reinterpret_cast<const bf16x8*>(ta + ks * 512);
        }
    }

    // ---- reductions. All waves passed the c=7 barrier (vs[0] dead). ----
#pragma unroll
    for (int reg = 0; reg < 16; ++reg) {
        float m = fmaxf(acc[0][reg], acc[1][reg]);
        if (vh == 0) {
            m = fmaxf(m, acc[2][reg]);
            m = fmaxf(m, acc[3][reg]);
        } else if (l32 < 4) {
            m = fmaxf(m, acc[2][reg]);            // vt6: cols 192..195 valid
        }
        m = fmaxf(m, __shfl_xor(m, 1));
        m = fmaxf(m, __shfl_xor(m, 2));
        m = fmaxf(m, __shfl_xor(m, 4));
        m = fmaxf(m, __shfl_xor(m, 8));
        m = fmaxf(m, __shfl_xor(m, 16));
        if (l32 == 0) {
            int row = tt * 32 + (reg & 3) + 8 * (reg >> 2) + 4 * h;
            red[(bhat * 2 + vh) * 64 + row] = m;
        }
    }
#pragma unroll
    for (int j = 0; j < 3; ++j) {
        float m = acc[j][0];
#pragma unroll
        for (int reg = 1; reg < 16; ++reg) m = fmaxf(m, acc[j][reg]);
        m = fmaxf(m, __shfl_xor(m, 32));          // combine h halves
        if (h == 0) red[256 + (bhat * 2 + tt) * 224 + (vt0 + j) * 32 + l32] = m;
    }
    if (vh == 0) {                                // j=3 (vt3)
        float m = acc[3][0];
#pragma unroll
        for (int reg = 1; reg < 16; ++reg) m = fmaxf(m, acc[3][reg]);
        m = fmaxf(m, __shfl_xor(m, 32));
        if (h == 0) red[256 + (bhat * 2 + tt) * 224 + 3 * 32 + l32] = m;
    }
    __syncthreads();

    if (wave == 0) {
#pragma unroll
        for (int bi = 0; bi < 2; ++bi) {
            float t = fmaxf(red[(bi * 2 + 0) * 64 + lane],
                            red[(bi * 2 + 1) * 64 + lane]);
            float cc = 0.f;
            for (int v = lane; v < 196; v += 64)
                cc += fmaxf(red[256 + (bi * 2 + 0) * 224 + v],
                            red[256 + (bi * 2 + 1) * 224 + v]);
#pragma unroll
            for (int mk = 1; mk <= 32; mk <<= 1) {
                t  += __shfl_xor(t, mk);
                cc += __shfl_xor(cc, mk);
            }
            if (lane == 0)
                sim[(size_t)(bp * 2 + bi) * 128 + q] =
                    0.5f * (t * (1.0f / 196.0f) + cc * (1.0f / 64.0f));
        }
    }
}

// ---------------------------------------------------------------------------
// MaxSim v5 (legacy linear-mirror path, tier-1 ws fallback) — unchanged.
// ---------------------------------------------------------------------------
__global__ __launch_bounds__(256) void maxsim32(
    const bf16_t* __restrict__ te,  // [128,64,512]
    const bf16_t* __restrict__ ve,  // [128,196,512]
    float* __restrict__ sim)        // [128,128] (b major)
{
    const int tid  = threadIdx.x;
    const int wave = tid >> 6;
    const int lane = tid & 63;
    const int l32  = lane & 31;
    const int h    = lane >> 5;
    const int bhat = wave >> 1;
    const int tt   = wave & 1;

    const int n  = blockIdx.x;
    const int q  = n >> 6;
    const int bp = n & 63;
    const int b  = bp * 2 + bhat;

    __shared__ bf16_t vs[2][224 * 64];
    __shared__ float  tmax_s[2][64];
    __shared__ float  vmax_s[2][2][224];

    f32x16 acc[7];
#pragma unroll
    for (int vt = 0; vt < 7; ++vt)
#pragma unroll
        for (int r = 0; r < 16; ++r) acc[vt][r] = 0.f;

    auto issue = [&](int buf, int c) {
        for (int g = wave; g < 28; g += 4) {
            int r   = g * 8 + (lane >> 3);
            int sr  = r < 196 ? r : 195;
            int seg = (lane & 7) ^ (lane >> 3);
            gload_lds16(ve + ((size_t)q * 196 + sr) * 512 + c * 64 + seg * 8,
                        &vs[buf][g * 512]);
        }
    };

    const size_t tbase = ((size_t)b * 64 + tt * 32 + l32) * 512;

    issue(0, 0);
#pragma unroll
    for (int c = 0; c < 8; ++c) {
        __syncthreads();
        if (c < 7) issue((c + 1) & 1, c + 1);
        bf16x8 a[4];
#pragma unroll
        for (int ks = 0; ks < 4; ++ks)
            a[ks] = *reinterpret_cast<const bf16x8*>(
                te + tbase + c * 64 + ks * 16 + h * 8);
        const int buf = c & 1;
#pragma unroll
        for (int ks = 0; ks < 4; ++ks)
#pragma unroll
            for (int vt = 0; vt < 7; ++vt) {
                int row  = vt * 32 + l32;
                int phys = (ks * 2 + h) ^ (row & 7);
                bf16x8 bv = *reinterpret_cast<const bf16x8*>(
                    &vs[buf][row * 64 + phys * 8]);
                acc[vt] = MFMA32(a[ks], bv, acc[vt]);
            }
    }

#pragma unroll
    for (int reg = 0; reg < 16; ++reg) {
        float m = acc[0][reg];
#pragma unroll
        for (int vt = 1; vt < 6; ++vt) m = fmaxf(m, acc[vt][reg]);
        if (l32 < 4) m = fmaxf(m, acc[6][reg]);
        m = fmaxf(m, __shfl_xor(m, 1));
        m = fmaxf(m, __shfl_xor(m, 2));
        m = fmaxf(m, __shfl_xor(m, 4));
        m = fmaxf(m, __shfl_xor(m, 8));
        m = fmaxf(m, __shfl_xor(m, 16));
        if (l32 == 0) {
            int row = tt * 32 + (reg & 3) + 8 * (reg >> 2) + 4 * h;
            tmax_s[bhat][row] = m;
        }
    }
#pragma unroll
    for (int vt = 0; vt < 7; ++vt) {
        float m = acc[vt][0];
#pragma unroll
        for (int reg = 1; reg < 16; ++reg) m = fmaxf(m, acc[vt][reg]);
        m = fmaxf(m, __shfl_xor(m, 32));
        if (h == 0) vmax_s[bhat][tt][vt * 32 + l32] = m;
    }
    __syncthreads();

    if (wave == 0) {
        float t0 = tmax_s[0][lane];
        float t1 = tmax_s[1][lane];
        float c0 = 0.f, c1 = 0.f;
        for (int v = lane; v < 196; v += 64) {
            c0 += fmaxf(vmax_s[0][0][v], vmax_s[0][1][v]);
            c1 += fmaxf(vmax_s[1][0][v], vmax_s[1][1][v]);
        }
#pragma unroll
        for (int mk = 1; mk <= 32; mk <<= 1) {
            t0 += __shfl_xor(t0, mk);
            t1 += __shfl_xor(t1, mk);
            c0 += __shfl_xor(c0, mk);
            c1 += __shfl_xor(c1, mk);
        }
        if (lane == 0) {
            sim[(size_t)(bp * 2 + 0) * 128 + q] = 0.5f * (t0 * (1.0f / 196.0f) + c0 * (1.0f / 64.0f));
            sim[(size_t)(bp * 2 + 1) * 128 + q] = 0.5f * (t1 * (1.0f / 196.0f) + c1 * (1.0f / 64.0f));
        }
    }
}

// ---------------------------------------------------------------------------
// Fallback projection (f32 weights, 16-row blocks) — used only if ws too small
// ---------------------------------------------------------------------------
__global__ __launch_bounds__(256) void proj_fb(
    const float* __restrict__ A, const float* __restrict__ Wf,
    const float* __restrict__ bias, float* __restrict__ out, int do_l2)
{
    const int tid  = threadIdx.x;
    const int wave = tid >> 6;
    const int lane = tid & 63;
    const int l16  = lane & 15;
    const int quad = lane >> 4;
    const int m0   = blockIdx.x * 16;
    const int e0   = wave * 128;

    f32x4 acc[8];
#pragma unroll
    for (int t = 0; t < 8; ++t) acc[t] = (f32x4){0.f, 0.f, 0.f, 0.f};
    const float* arow = A + (size_t)(m0 + l16) * 768 + quad * 8;
    for (int k0 = 0; k0 < 768; k0 += 32) {
        bf16x8 af = cvt8(arow + k0);
#pragma unroll
        for (int t = 0; t < 8; ++t) {
            bf16x8 wv = cvt8(Wf + (size_t)(e0 + t * 16 + l16) * 768 + quad * 8 + k0);
            acc[t] = MFMA16(af, wv, acc[t]);
        }
    }
#pragma unroll
    for (int t = 0; t < 8; ++t) {
        float bv = bias[e0 + t * 16 + l16];
#pragma unroll
        for (int r = 0; r < 4; ++r) acc[t][r] += bv;
    }
    float inv[4] = {1.f, 1.f, 1.f, 1.f};
    __shared__ float sq[4][16];
    if (do_l2) {
#pragma unroll
        for (int r = 0; r < 4; ++r) {
            float s = 0.f;
#pragma unroll
            for (int t = 0; t < 8; ++t) s += acc[t][r] * acc[t][r];
            s += __shfl_xor(s, 1); s += __shfl_xor(s, 2);
            s += __shfl_xor(s, 4); s += __shfl_xor(s, 8);
            if (l16 == 0) sq[wave][quad * 4 + r] = s;
        }
        __syncthreads();
#pragma unroll
        for (int r = 0; r < 4; ++r) {
            float tot = sq[0][quad * 4 + r] + sq[1][quad * 4 + r]
                      + sq[2][quad * 4 + r] + sq[3][quad * 4 + r];
            inv[r] = 1.0f / fmaxf(sqrtf(tot), 1e-12f);
        }
    }
#pragma unroll
    for (int t = 0; t < 8; ++t)
#pragma unroll
        for (int r = 0; r < 4; ++r)
            out[(size_t)(m0 + quad * 4 + r) * 512 + (e0 + t * 16 + l16)] =
                acc[t][r] * inv[r];
}

// ---------------------------------------------------------------------------
// Fallback maxsim (f32 operands from d_out, 16x16 path) — ws-too-small only
// ---------------------------------------------------------------------------
__global__ __launch_bounds__(256) void maxsim_fb(
    const float* __restrict__ te, const float* __restrict__ ve,
    float* __restrict__ sim)
{
    const int tid  = threadIdx.x;
    const int wave = tid >> 6;
    const int lane = tid & 63;
    const int l16  = lane & 15;
    const int quad = lane >> 4;
    const int q    = blockIdx.x >> 6;
    const int bp   = blockIdx.x & 63;

    __shared__ bf16_t vsl[208 * 72];
    __shared__ float  maxt_s[2][4][208];
    __shared__ float  t2v_part[2][4];

    f32x4 acc0[13], acc1[13];
#pragma unroll
    for (int vt = 0; vt < 13; ++vt) {
        acc0[vt] = (f32x4){0.f, 0.f, 0.f, 0.f};
        acc1[vt] = (f32x4){0.f, 0.f, 0.f, 0.f};
    }
    const size_t toff0 = ((size_t)(bp * 2) * 64 + wave * 16 + l16) * 512 + quad * 8;
    const size_t toff1 = toff0 + (size_t)64 * 512;

    for (int k0 = 0; k0 < 512; k0 += 64) {
        __syncthreads();
        for (int s = tid; s < 416; s += 256) {
            const int row  = s >> 1;
            const int half = s & 1;
            const int vsrc = row < 196 ? row : 195;
            bf16x8 tmp[4];
            const size_t goff = ((size_t)q * 196 + vsrc) * 512 + k0 + half * 32;
#pragma unroll
            for (int j = 0; j < 4; ++j) tmp[j] = cvt8(ve + goff + j * 8);
            bf16_t* dst = &vsl[row * 72 + half * 32];
#pragma unroll
            for (int j = 0; j < 4; ++j)
                *reinterpret_cast<bf16x8*>(dst + j * 8) = tmp[j];
        }
        __syncthreads();
#pragma unroll
        for (int ks = 0; ks < 2; ++ks) {
            bf16x8 a0 = cvt8(te + toff0 + k0 + ks * 32);
            bf16x8 a1 = cvt8(te + toff1 + k0 + ks * 32);
#pragma unroll
            for (int vt = 0; vt < 13; ++vt) {
                bf16x8 bv = *reinterpret_cast<const bf16x8*>(
                    &vsl[(vt * 16 + l16) * 72 + ks * 32 + quad * 8]);
                acc0[vt] = MFMA16(a0, bv, acc0[vt]);
                acc1[vt] = MFMA16(a1, bv, acc1[vt]);
            }
        }
    }
#pragma unroll
    for (int bi = 0; bi < 2; ++bi) {
        const f32x4* acc = bi ? acc1 : acc0;
        float sum_maxv = 0.f;
#pragma unroll
        for (int r = 0; r < 4; ++r) {
            float m = -3.0e38f;
#pragma unroll
            for (int vt = 0; vt < 13; ++vt) {
                int v = vt * 16 + l16;
                if (v < 196) m = fmaxf(m, acc[vt][r]);
            }
            m = fmaxf(m, __shfl_xor(m, 1));
            m = fmaxf(m, __shfl_xor(m, 2));
            m = fmaxf(m, __shfl_xor(m, 4));
            m = fmaxf(m, __shfl_xor(m, 8));
            sum_maxv += m;
        }
        sum_maxv += __shfl_xor(sum_maxv, 16);
        sum_maxv += __shfl_xor(sum_maxv, 32);
        if (lane == 0) t2v_part[bi][wave] = sum_maxv;
#pragma unroll
        for (int vt = 0; vt < 13; ++vt) {
            float m = fmaxf(fmaxf(acc[vt][0], acc[vt][1]),
                            fmaxf(acc[vt][2], acc[vt][3]));
            m = fmaxf(m, __shfl_xor(m, 16));
            m = fmaxf(m, __shfl_xor(m, 32));
            if (lane < 16) maxt_s[bi][wave][vt * 16 + l16] = m;
        }
    }
    __syncthreads();
    if (wave == 0) {
#pragma unroll
        for (int bi = 0; bi < 2; ++bi) {
            float s_row = t2v_part[bi][0] + t2v_part[bi][1]
                        + t2v_part[bi][2] + t2v_part[bi][3];
            float s_col = 0.f;
            for (int v = lane; v < 196; v += 64) {
                float m = fmaxf(fmaxf(maxt_s[bi][0][v], maxt_s[bi][1][v]),
                                fmaxf(maxt_s[bi][2][v], maxt_s[bi][3][v]));
                s_col += m;
            }
            s_col += __shfl_xor(s_col, 1);
            s_col += __shfl_xor(s_col, 2);
            s_col += __shfl_xor(s_col, 4);
            s_col += __shfl_xor(s_col, 8);
            s_col += __shfl_xor(s_col, 16);
            s_col += __shfl_xor(s_col, 32);
            if (lane == 0)
                sim[(size_t)(bp * 2 + bi) * 128 + q] =
                    0.5f * (s_row * (1.0f / 196.0f) + s_col * (1.0f / 64.0f));
        }
    }
}

// ---------------------------------------------------------------------------
// text_mask[b,t] = (t < len[b]); int64-vs-int32 auto-detect (lengths 1..64).
// ---------------------------------------------------------------------------
__global__ void mask_kernel(const int* __restrict__ len, float* __restrict__ mask)
{
    int i = blockIdx.x * 256 + threadIdx.x;
    int is64 = (len[1] == 0) ? 1 : 0;
    if (i < 128 * 64) {
        int b = i >> 6;
        int t = i & 63;
        int L = is64 ? len[2 * b] : len[b];
        mask[i] = (t < L) ? 1.0f : 0.0f;
    }
}

extern "C" void kernel_launch(void* const* d_in, const int* in_sizes, int n_in,
                              void* d_out, int out_size, void* d_ws, size_t ws_size,
                              hipStream_t stream)
{
    int idx[13] = {0, 1, 2, 3, 4, 5, 6, 7, 8, 9, 10, 11, 12};
    if (in_sizes && n_in >= 13) {
        bool dict = (in_sizes[2] == 19267584) && (in_sizes[4] == 393216);
        if (!dict) {
            static const int alpha_sizes[13] = {393216, 393216, 393216, 393216,
                                                512, 512, 512, 512, 128,
                                                98304, 6291456, 98304, 19267584};
            bool alpha = true;
            for (int i = 0; i < 13; ++i)
                if (in_sizes[i] != alpha_sizes[i]) { alpha = false; break; }
            if (alpha) {
                const int m[13] = {11, 9, 12, 10, 2, 6, 0, 4, 3, 7, 1, 5, 8};
                for (int i = 0; i < 13; ++i) idx[i] = m[i];
            }
        }
    }

    const float* visual_cls     = (const float*)d_in[idx[0]];
    const float* textual_cls    = (const float*)d_in[idx[1]];
    const float* visual_tokens  = (const float*)d_in[idx[2]];
    const float* textual_tokens = (const float*)d_in[idx[3]];
    const float* Wv_cls = (const float*)d_in[idx[4]];
    const float* bv_cls = (const float*)d_in[idx[5]];
    const float* Wt_cls = (const float*)d_in[idx[6]];
    const float* bt_cls = (const float*)d_in[idx[7]];
    const float* Wv_tok = (const float*)d_in[idx[8]];
    const float* bv_tok = (const float*)d_in[idx[9]];
    const float* Wt_tok = (const float*)d_in[idx[10]];
    const float* bt_tok = (const float*)d_in[idx[11]];
    const int*   text_length = (const int*)d_in[idx[12]];

    float* out    = (float*)d_out;
    float* o_vcls = out;
    float* o_tcls = out + 65536;
    float* o_ve   = out + 131072;
    float* o_te   = out + 12976128;
    float* o_mask = out + 17170432;
    float* o_sim  = out + 17178624;

    const size_t NVE = 12845056;   // linear bf16 ve mirror (tier-1)
    const size_t NTE = 4194304;
    const size_t need_new = (4 * (size_t)WN + VP_ELEMS + TP_ELEMS) * 2;   // 40.9 MB
    const size_t need_old = (4 * (size_t)WN + NVE + NTE) * 2;             // 37.2 MB

    dim3 blk(256);
    if (ws_size >= need_new) {
        bf16_t* w_all = (bf16_t*)d_ws;
        bf16_t* vp    = w_all + 4 * (size_t)WN;
        bf16_t* tp    = vp + VP_ELEMS;
        prep_all<<<1824, blk, 0, stream>>>(Wv_cls, Wt_cls, Wv_tok, Wt_tok,
                                           w_all, vp, text_length, o_mask);
        proj_all<1><<<1048, blk, 0, stream>>>(visual_tokens, textual_tokens,
                                              visual_cls, textual_cls, w_all,
                                              bv_cls, bt_cls, bv_tok, bt_tok,
                                              out, vp, tp);
        maxsim32p<<<128 * 64, dim3(512), 0, stream>>>(tp, vp, o_sim);
    } else if (ws_size >= need_old) {
        bf16_t* w_all = (bf16_t*)d_ws;
        bf16_t* b_ve  = w_all + 4 * (size_t)WN;
        bf16_t* b_te  = b_ve + NVE;
        cvt_w4<<<768, blk, 0, stream>>>(Wv_cls, Wt_cls, Wv_tok, Wt_tok, w_all);
        proj_all<0><<<1048, blk, 0, stream>>>(visual_tokens, textual_tokens,
                                              visual_cls, textual_cls, w_all,
                                              bv_cls, bt_cls, bv_tok, bt_tok,
                                              out, b_ve, b_te);
        mask_kernel<<<32, blk, 0, stream>>>(text_length, o_mask);
        maxsim32<<<128 * 64, blk, 0, stream>>>(b_te, b_ve, o_sim);
    } else {
        proj_fb<<<8,    blk, 0, stream>>>(visual_cls,     Wv_cls, bv_cls, o_vcls, 0);
        proj_fb<<<8,    blk, 0, stream>>>(textual_cls,    Wt_cls, bt_cls, o_tcls, 0);
        proj_fb<<<1568, blk, 0, stream>>>(visual_tokens,  Wv_tok, bv_tok, o_ve, 1);
        proj_fb<<<512,  blk, 0, stream>>>(textual_tokens, Wt_tok, bt_tok, o_te, 1);
        mask_kernel<<<32, blk, 0, stream>>>(text_length, o_mask);
        maxsim_fb<<<128 * 64, blk, 0, stream>>>(o_te, o_ve, o_sim);
    }
}